// Round 1
// baseline (1279.613 us; speedup 1.0000x reference)
//
#include <hip/hip_runtime.h>
#include <math.h>

// Problem constants
#define B_DIM 128
#define C_DIM 2048
#define HW2   196   // 14*14

// ---------------------------------------------------------------------------
// K1: per-(b,c) 14x14 tile -> global max (mp) + 4-scale adaptive avg-pool max (ms)
// one wave (64 lanes) per tile; block = 4 waves
// ---------------------------------------------------------------------------
__global__ __launch_bounds__(256) void pool_max_kernel(
    const float* __restrict__ x, float* __restrict__ mp, float* __restrict__ ms) {
  __shared__ float tile[4][196];
  const int w = threadIdx.x >> 6;
  const int lane = threadIdx.x & 63;
  const size_t t = (size_t)blockIdx.x * 4 + w;   // tile id = b*C + c
  const float* src = x + t * HW2;
  float v0 = src[lane];
  float v1 = src[64 + lane];
  float v2 = src[128 + lane];
  float v3 = -INFINITY;
  tile[w][lane] = v0;
  tile[w][64 + lane] = v1;
  tile[w][128 + lane] = v2;
  if (lane < 4) { v3 = src[192 + lane]; tile[w][192 + lane] = v3; }
  __syncthreads();

  // global max
  float m = fmaxf(fmaxf(v0, v1), fmaxf(v2, v3));
  #pragma unroll
  for (int off = 32; off > 0; off >>= 1) m = fmaxf(m, __shfl_xor(m, off));
  if (lane == 0) mp[t] = m;

  // 211 bins across scales {4,5,7,11}; lane g handles bins g, g+64, g+128, g+192
  float smax0 = -INFINITY, smax1 = -INFINITY, smax2 = -INFINITY, smax3 = -INFINITY;
  for (int g = lane; g < 211; g += 64) {
    int k, base, sc;
    if (g < 16)      { k = 4;  base = 0;  sc = 0; }
    else if (g < 41) { k = 5;  base = 16; sc = 1; }
    else if (g < 90) { k = 7;  base = 41; sc = 2; }
    else             { k = 11; base = 90; sc = 3; }
    int idx = g - base;
    int bi = idx / k;
    int bj = idx - bi * k;
    int rs = (bi * 14) / k, re = ((bi + 1) * 14 + k - 1) / k;
    int cs = (bj * 14) / k, ce = ((bj + 1) * 14 + k - 1) / k;
    float s = 0.f;
    for (int r = rs; r < re; ++r)
      for (int cc = cs; cc < ce; ++cc)
        s += tile[w][r * 14 + cc];
    float val = s / (float)((re - rs) * (ce - cs));
    if (sc == 0)      smax0 = fmaxf(smax0, val);
    else if (sc == 1) smax1 = fmaxf(smax1, val);
    else if (sc == 2) smax2 = fmaxf(smax2, val);
    else              smax3 = fmaxf(smax3, val);
  }
  #pragma unroll
  for (int off = 32; off > 0; off >>= 1) {
    smax0 = fmaxf(smax0, __shfl_xor(smax0, off));
    smax1 = fmaxf(smax1, __shfl_xor(smax1, off));
    smax2 = fmaxf(smax2, __shfl_xor(smax2, off));
    smax3 = fmaxf(smax3, __shfl_xor(smax3, off));
  }
  if (lane == 0) {
    float* o = ms + t * 4;
    o[0] = smax0; o[1] = smax1; o[2] = smax2; o[3] = smax3;
  }
}

// ---------------------------------------------------------------------------
// column stats over batch (128 rows): mean + rsqrt(biased var + 1e-5)
// ---------------------------------------------------------------------------
__global__ void colstats_kernel(const float* __restrict__ X,
                                float* __restrict__ mean, float* __restrict__ rstd,
                                int N) {
  int c = blockIdx.x * 256 + threadIdx.x;
  if (c >= N) return;
  float s = 0.f, q = 0.f;
  for (int b = 0; b < B_DIM; ++b) {
    float v = X[(size_t)b * N + c];
    s += v; q += v * v;
  }
  float m = s * (1.f / B_DIM);
  float var = q * (1.f / B_DIM) - m * m;
  if (var < 0.f) var = 0.f;
  mean[c] = m;
  rstd[c] = rsqrtf(var + 1e-5f);
}

// ---------------------------------------------------------------------------
// gate: logits[b,j] = sum_c elu(bn(mp[b,c])) * g_w[j,c] + g_b[j]; sidx = argmax
// one block per batch row
// ---------------------------------------------------------------------------
__global__ void gate_kernel(const float* __restrict__ mp,
                            const float* __restrict__ mean, const float* __restrict__ rstd,
                            const float* __restrict__ gg, const float* __restrict__ gb,
                            const float* __restrict__ gw, const float* __restrict__ gbias,
                            int* __restrict__ sidx) {
  const int b = blockIdx.x;
  const int t = threadIdx.x;
  float s0 = 0.f, s1 = 0.f, s2 = 0.f, s3 = 0.f;
  for (int c = t; c < C_DIM; c += 256) {
    float v = mp[(size_t)b * C_DIM + c];
    float xn = (v - mean[c]) * rstd[c] * gg[c] + gb[c];
    float e = xn > 0.f ? xn : expm1f(xn);
    s0 += e * gw[c];
    s1 += e * gw[C_DIM + c];
    s2 += e * gw[2 * C_DIM + c];
    s3 += e * gw[3 * C_DIM + c];
  }
  __shared__ float red[4][256];
  red[0][t] = s0; red[1][t] = s1; red[2][t] = s2; red[3][t] = s3;
  __syncthreads();
  for (int st = 128; st > 0; st >>= 1) {
    if (t < st) {
      red[0][t] += red[0][t + st];
      red[1][t] += red[1][t + st];
      red[2][t] += red[2][t + st];
      red[3][t] += red[3][t + st];
    }
    __syncthreads();
  }
  if (t == 0) {
    float best = red[0][0] + gbias[0];
    int bi = 0;
    for (int j = 1; j < 4; ++j) {
      float l = red[j][0] + gbias[j];
      if (l > best) { best = l; bi = j; }   // first-max semantics like jnp.argmax
    }
    sidx[b] = bi;
  }
}

// ---------------------------------------------------------------------------
// gated scale select: pool[b,c] = ms[b,c,sidx[b]]
// ---------------------------------------------------------------------------
__global__ void pool_select_kernel(const float* __restrict__ ms,
                                   const int* __restrict__ sidx,
                                   float* __restrict__ pool) {
  int i = blockIdx.x * 256 + threadIdx.x;
  if (i >= B_DIM * C_DIM) return;
  pool[i] = ms[(size_t)i * 4 + sidx[i >> 11]];
}

// ---------------------------------------------------------------------------
// generic fp32 GEMM: C[128,N] = A[128,K] @ W[N,K]^T + bias[N]
// 32x32 tile, BK=32, 2x2 micro-tile, 256 threads
// ---------------------------------------------------------------------------
__global__ __launch_bounds__(256) void gemm_bias_kernel(
    const float* __restrict__ A, const float* __restrict__ Wt,
    const float* __restrict__ bias, float* __restrict__ C,
    int N, int K) {
  __shared__ float As[32][34];
  __shared__ float Bs[32][34];
  const int t = threadIdx.x;
  const int lk = t & 31;
  const int lr = t >> 5;        // 0..7
  const int tx = t & 15;
  const int ty = t >> 4;
  const int m0 = blockIdx.y << 5;
  const int n0 = blockIdx.x << 5;
  float a00 = 0.f, a01 = 0.f, a10 = 0.f, a11 = 0.f;
  for (int k0 = 0; k0 < K; k0 += 32) {
    #pragma unroll
    for (int p = 0; p < 4; ++p) {
      int r = lr + (p << 3);
      As[lk][r] = A[(size_t)(m0 + r) * K + (k0 + lk)];
      int n = n0 + r;
      Bs[lk][r] = (n < N) ? Wt[(size_t)n * K + (k0 + lk)] : 0.f;
    }
    __syncthreads();
    #pragma unroll
    for (int kk = 0; kk < 32; ++kk) {
      float x0 = As[kk][ty * 2], x1 = As[kk][ty * 2 + 1];
      float w0 = Bs[kk][tx * 2], w1 = Bs[kk][tx * 2 + 1];
      a00 = fmaf(x0, w0, a00); a01 = fmaf(x0, w1, a01);
      a10 = fmaf(x1, w0, a10); a11 = fmaf(x1, w1, a11);
    }
    __syncthreads();
  }
  int m = m0 + ty * 2, n = n0 + tx * 2;
  if (n < N) {
    C[(size_t)m * N + n] = a00 + bias[n];
    C[(size_t)(m + 1) * N + n] = a10 + bias[n];
  }
  if (n + 1 < N) {
    C[(size_t)m * N + n + 1] = a01 + bias[n + 1];
    C[(size_t)(m + 1) * N + n + 1] = a11 + bias[n + 1];
  }
}

// ---------------------------------------------------------------------------
// BN apply (+optional relu/elu): Y[b, off+c] = act((X[b,c]-mean[c])*rstd[c]*g[c]+bta[c])
// MODE: 0 none, 1 relu, 2 elu
// ---------------------------------------------------------------------------
template <int MODE>
__global__ void bn_apply_kernel(const float* __restrict__ X,
                                const float* __restrict__ mean, const float* __restrict__ rstd,
                                const float* __restrict__ g, const float* __restrict__ bta,
                                float* __restrict__ Y,
                                int N, int outStride, int outColOff) {
  int i = blockIdx.x * 256 + threadIdx.x;
  if (i >= B_DIM * N) return;
  int b = i / N;
  int c = i - b * N;
  float v = (X[i] - mean[c]) * rstd[c] * g[c] + bta[c];
  if (MODE == 1) v = fmaxf(v, 0.f);
  if (MODE == 2) v = v > 0.f ? v : expm1f(v);
  Y[(size_t)b * outStride + outColOff + c] = v;
}

// ---------------------------------------------------------------------------
extern "C" void kernel_launch(void* const* d_in, const int* in_sizes, int n_in,
                              void* d_out, int out_size, void* d_ws, size_t ws_size,
                              hipStream_t stream) {
  const float* x      = (const float*)d_in[0];
  const float* g_bn_g = (const float*)d_in[1];
  const float* g_bn_b = (const float*)d_in[2];
  const float* g_w    = (const float*)d_in[3];
  const float* g_b    = (const float*)d_in[4];
  const float* e_w    = (const float*)d_in[5];
  const float* e_b    = (const float*)d_in[6];
  const float* e_g    = (const float*)d_in[7];
  const float* e_bb   = (const float*)d_in[8];
  const float* hl_g1  = (const float*)d_in[9];
  const float* hl_b1  = (const float*)d_in[10];
  const float* hl_w1  = (const float*)d_in[11];
  const float* hl_bi1 = (const float*)d_in[12];
  const float* hl_g2  = (const float*)d_in[13];
  const float* hl_b2  = (const float*)d_in[14];
  const float* hl_w2  = (const float*)d_in[15];
  const float* hl_bi2 = (const float*)d_in[16];
  const float* hh_g1  = (const float*)d_in[17];
  const float* hh_b1  = (const float*)d_in[18];
  const float* hh_w1  = (const float*)d_in[19];
  const float* hh_bi1 = (const float*)d_in[20];
  const float* hh_g2  = (const float*)d_in[21];
  const float* hh_b2  = (const float*)d_in[22];
  const float* hh_w2  = (const float*)d_in[23];
  const float* hh_bi2 = (const float*)d_in[24];
  const float* hf_g1  = (const float*)d_in[25];
  const float* hf_b1  = (const float*)d_in[26];
  const float* hf_w1  = (const float*)d_in[27];
  const float* hf_bi1 = (const float*)d_in[28];
  const float* hf_g2  = (const float*)d_in[29];
  const float* hf_b2  = (const float*)d_in[30];
  const float* hf_w2  = (const float*)d_in[31];
  const float* hf_bi2 = (const float*)d_in[32];
  float* out = (float*)d_out;

  float* W = (float*)d_ws;
  const size_t BC = (size_t)B_DIM * C_DIM;   // 262144
  float* mp   = W;                   // [128,2048]
  float* ms   = mp + BC;             // [128,2048,4]
  float* pool = ms + BC * 4;         // [128,2048]
  float* y    = pool + BC;           // [128,2048]
  float* xl   = y + BC;              // [128,2048]
  float* an_l = xl + BC;             // [128,2048]
  float* an_h = an_l + BC;           // [128,2048]
  float* an_f = an_h + BC;           // [128,4096]
  float* h1_l = an_f + BC * 2;       // [128,512]
  float* h1_h = h1_l + 128 * 512;
  float* h1_f = h1_h + 128 * 512;    // [128,1024]
  float* a2_l = h1_f + 128 * 1024;
  float* a2_h = a2_l + 128 * 512;
  float* a2_f = a2_h + 128 * 512;    // [128,1024]
  float* st   = a2_f + 128 * 1024;
  float* mean_mp = st;          float* rstd_mp = st + 2048;
  float* mean_y  = st + 4096;   float* rstd_y  = st + 6144;
  float* mean_xl = st + 8192;   float* rstd_xl = st + 10240;
  float* m1l = st + 12288;      float* r1l = st + 12800;
  float* m1h = st + 13312;      float* r1h = st + 13824;
  float* m1f = st + 14336;      float* r1f = st + 15360;
  int* sidx = (int*)(st + 16384);

  // Stage A: pooling pass over x
  pool_max_kernel<<<65536, 256, 0, stream>>>(x, mp, ms);

  // Stage B: gate
  colstats_kernel<<<8, 256, 0, stream>>>(mp, mean_mp, rstd_mp, 2048);
  gate_kernel<<<128, 256, 0, stream>>>(mp, mean_mp, rstd_mp, g_bn_g, g_bn_b, g_w, g_b, sidx);
  pool_select_kernel<<<1024, 256, 0, stream>>>(ms, sidx, pool);

  // expert_low: y = pool @ e_w^T + e_b ; xl = relu(bn(y))
  gemm_bias_kernel<<<dim3(64, 4), 256, 0, stream>>>(pool, e_w, e_b, y, 2048, 2048);
  colstats_kernel<<<8, 256, 0, stream>>>(y, mean_y, rstd_y, 2048);
  bn_apply_kernel<1><<<1024, 256, 0, stream>>>(y, mean_y, rstd_y, e_g, e_bb, xl, 2048, 2048, 0);
  colstats_kernel<<<8, 256, 0, stream>>>(xl, mean_xl, rstd_xl, 2048);

  // head BN1 inputs (hh reuses mp stats; hf reuses xl+mp stats)
  bn_apply_kernel<0><<<1024, 256, 0, stream>>>(xl, mean_xl, rstd_xl, hl_g1, hl_b1, an_l, 2048, 2048, 0);
  bn_apply_kernel<0><<<1024, 256, 0, stream>>>(mp, mean_mp, rstd_mp, hh_g1, hh_b1, an_h, 2048, 2048, 0);
  bn_apply_kernel<0><<<1024, 256, 0, stream>>>(xl, mean_xl, rstd_xl, hf_g1, hf_b1, an_f, 2048, 4096, 0);
  bn_apply_kernel<0><<<1024, 256, 0, stream>>>(mp, mean_mp, rstd_mp, hf_g1 + 2048, hf_b1 + 2048, an_f, 2048, 4096, 2048);

  // head linear1
  gemm_bias_kernel<<<dim3(16, 4), 256, 0, stream>>>(an_l, hl_w1, hl_bi1, h1_l, 512, 2048);
  gemm_bias_kernel<<<dim3(16, 4), 256, 0, stream>>>(an_h, hh_w1, hh_bi1, h1_h, 512, 2048);
  gemm_bias_kernel<<<dim3(32, 4), 256, 0, stream>>>(an_f, hf_w1, hf_bi1, h1_f, 1024, 4096);

  // head BN2 + elu
  colstats_kernel<<<2, 256, 0, stream>>>(h1_l, m1l, r1l, 512);
  colstats_kernel<<<2, 256, 0, stream>>>(h1_h, m1h, r1h, 512);
  colstats_kernel<<<4, 256, 0, stream>>>(h1_f, m1f, r1f, 1024);
  bn_apply_kernel<2><<<256, 256, 0, stream>>>(h1_l, m1l, r1l, hl_g2, hl_b2, a2_l, 512, 512, 0);
  bn_apply_kernel<2><<<256, 256, 0, stream>>>(h1_h, m1h, r1h, hh_g2, hh_b2, a2_h, 512, 512, 0);
  bn_apply_kernel<2><<<512, 256, 0, stream>>>(h1_f, m1f, r1f, hf_g2, hf_b2, a2_f, 1024, 1024, 0);

  // head linear2 -> outputs (out_low, out_high, out) concatenated
  gemm_bias_kernel<<<dim3(7, 4), 256, 0, stream>>>(a2_l, hl_w2, hl_bi2, out, 200, 512);
  gemm_bias_kernel<<<dim3(7, 4), 256, 0, stream>>>(a2_h, hh_w2, hh_bi2, out + 25600, 200, 512);
  gemm_bias_kernel<<<dim3(7, 4), 256, 0, stream>>>(a2_f, hf_w2, hf_bi2, out + 51200, 200, 1024);
}

// Round 2
// 415.695 us; speedup vs baseline: 3.0783x; 3.0783x over previous
//
#include <hip/hip_runtime.h>
#include <math.h>

#define B_DIM 128
#define C_DIM 2048
#define HW2   196

// ---------------------------------------------------------------------------
// K1: per-(b,c) 14x14 tile -> global max (mp) + 4-scale adaptive avg-pool max (ms)
// one wave per tile; block = 4 waves
// ---------------------------------------------------------------------------
__global__ __launch_bounds__(256) void pool_max_kernel(
    const float* __restrict__ x, float* __restrict__ mp, float* __restrict__ ms) {
  __shared__ float tile[4][196];
  const int w = threadIdx.x >> 6;
  const int lane = threadIdx.x & 63;
  const size_t t = (size_t)blockIdx.x * 4 + w;
  const float* src = x + t * HW2;
  float v0 = src[lane];
  float v1 = src[64 + lane];
  float v2 = src[128 + lane];
  float v3 = -INFINITY;
  tile[w][lane] = v0;
  tile[w][64 + lane] = v1;
  tile[w][128 + lane] = v2;
  if (lane < 4) { v3 = src[192 + lane]; tile[w][192 + lane] = v3; }
  __syncthreads();

  float m = fmaxf(fmaxf(v0, v1), fmaxf(v2, v3));
  #pragma unroll
  for (int off = 32; off > 0; off >>= 1) m = fmaxf(m, __shfl_xor(m, off));
  if (lane == 0) mp[t] = m;

  float smax0 = -INFINITY, smax1 = -INFINITY, smax2 = -INFINITY, smax3 = -INFINITY;
  for (int g = lane; g < 211; g += 64) {
    int k, base, sc;
    if (g < 16)      { k = 4;  base = 0;  sc = 0; }
    else if (g < 41) { k = 5;  base = 16; sc = 1; }
    else if (g < 90) { k = 7;  base = 41; sc = 2; }
    else             { k = 11; base = 90; sc = 3; }
    int idx = g - base;
    int bi = idx / k;
    int bj = idx - bi * k;
    int rs = (bi * 14) / k, re = ((bi + 1) * 14 + k - 1) / k;
    int cs = (bj * 14) / k, ce = ((bj + 1) * 14 + k - 1) / k;
    float s = 0.f;
    for (int r = rs; r < re; ++r)
      for (int cc = cs; cc < ce; ++cc)
        s += tile[w][r * 14 + cc];
    float val = s / (float)((re - rs) * (ce - cs));
    if (sc == 0)      smax0 = fmaxf(smax0, val);
    else if (sc == 1) smax1 = fmaxf(smax1, val);
    else if (sc == 2) smax2 = fmaxf(smax2, val);
    else              smax3 = fmaxf(smax3, val);
  }
  #pragma unroll
  for (int off = 32; off > 0; off >>= 1) {
    smax0 = fmaxf(smax0, __shfl_xor(smax0, off));
    smax1 = fmaxf(smax1, __shfl_xor(smax1, off));
    smax2 = fmaxf(smax2, __shfl_xor(smax2, off));
    smax3 = fmaxf(smax3, __shfl_xor(smax3, off));
  }
  if (lane == 0) {
    float* o = ms + t * 4;
    o[0] = smax0; o[1] = smax1; o[2] = smax2; o[3] = smax3;
  }
}

// ---------------------------------------------------------------------------
// column stats over batch: mean + rsqrt(var+eps). block = 64 cols x 4 row-groups
// requires N % 64 == 0
// ---------------------------------------------------------------------------
__global__ void colstats_kernel(const float* __restrict__ X,
                                float* __restrict__ mean, float* __restrict__ rstd,
                                int N) {
  __shared__ float ss[4][64], qq[4][64];
  const int ci = threadIdx.x & 63, g = threadIdx.x >> 6;
  const int c = blockIdx.x * 64 + ci;
  float s = 0.f, q = 0.f;
  for (int b = g * 32; b < g * 32 + 32; ++b) {
    float v = X[(size_t)b * N + c];
    s += v; q += v * v;
  }
  ss[g][ci] = s; qq[g][ci] = q;
  __syncthreads();
  if (g == 0) {
    s = ss[0][ci] + ss[1][ci] + ss[2][ci] + ss[3][ci];
    q = qq[0][ci] + qq[1][ci] + qq[2][ci] + qq[3][ci];
    float m = s * (1.f / B_DIM);
    float var = q * (1.f / B_DIM) - m * m;
    if (var < 0.f) var = 0.f;
    mean[c] = m;
    rstd[c] = rsqrtf(var + 1e-5f);
  }
}

// ---------------------------------------------------------------------------
// gate: logits + argmax -> sidx
// ---------------------------------------------------------------------------
__global__ void gate_kernel(const float* __restrict__ mp,
                            const float* __restrict__ mean, const float* __restrict__ rstd,
                            const float* __restrict__ gg, const float* __restrict__ gb,
                            const float* __restrict__ gw, const float* __restrict__ gbias,
                            int* __restrict__ sidx) {
  const int b = blockIdx.x;
  const int t = threadIdx.x;
  float s0 = 0.f, s1 = 0.f, s2 = 0.f, s3 = 0.f;
  for (int c = t; c < C_DIM; c += 256) {
    float v = mp[(size_t)b * C_DIM + c];
    float xn = (v - mean[c]) * rstd[c] * gg[c] + gb[c];
    float e = xn > 0.f ? xn : expm1f(xn);
    s0 += e * gw[c];
    s1 += e * gw[C_DIM + c];
    s2 += e * gw[2 * C_DIM + c];
    s3 += e * gw[3 * C_DIM + c];
  }
  __shared__ float red[4][256];
  red[0][t] = s0; red[1][t] = s1; red[2][t] = s2; red[3][t] = s3;
  __syncthreads();
  for (int st = 128; st > 0; st >>= 1) {
    if (t < st) {
      red[0][t] += red[0][t + st];
      red[1][t] += red[1][t + st];
      red[2][t] += red[2][t + st];
      red[3][t] += red[3][t + st];
    }
    __syncthreads();
  }
  if (t == 0) {
    float best = red[0][0] + gbias[0];
    int bi = 0;
    for (int j = 1; j < 4; ++j) {
      float l = red[j][0] + gbias[j];
      if (l > best) { best = l; bi = j; }
    }
    sidx[b] = bi;
  }
}

__global__ void pool_select_kernel(const float* __restrict__ ms,
                                   const int* __restrict__ sidx,
                                   float* __restrict__ pool) {
  int i = blockIdx.x * 256 + threadIdx.x;
  if (i >= B_DIM * C_DIM) return;
  pool[i] = ms[(size_t)i * 4 + sidx[i >> 11]];
}

// ---------------------------------------------------------------------------
// split-K GEMM: P[z][m][n] partial of A[128,K(chunk z)] @ W[N,K]^T
// BM=64 BN=64 BK=32, 256 threads, 4x4 micro-tile, float4 everywhere
// grid: (ceil(N/64), 2, S); Kc = K/S must be multiple of 32
// ---------------------------------------------------------------------------
__global__ __launch_bounds__(256) void gemm_splitk_kernel(
    const float* __restrict__ A, const float* __restrict__ W,
    float* __restrict__ P, int N, int K, int Kc, int sliceStride) {
  __shared__ float As[32][68];
  __shared__ float Bs[32][68];
  const int t = threadIdx.x;
  const int m0 = blockIdx.y << 6;
  const int n0 = blockIdx.x << 6;
  const int kbeg = blockIdx.z * Kc;
  const int lr = t >> 3;            // 0..31
  const int lk4 = (t & 7) << 2;     // 0,4,...,28
  const int tx = t & 15, ty = t >> 4;
  float acc[4][4] = {{0.f}};
  const float4 z4 = make_float4(0.f, 0.f, 0.f, 0.f);
  for (int k0 = kbeg; k0 < kbeg + Kc; k0 += 32) {
    float4 a0 = *(const float4*)&A[(size_t)(m0 + lr) * K + k0 + lk4];
    float4 a1 = *(const float4*)&A[(size_t)(m0 + lr + 32) * K + k0 + lk4];
    int n1 = n0 + lr, n2 = n0 + lr + 32;
    float4 b0 = (n1 < N) ? *(const float4*)&W[(size_t)n1 * K + k0 + lk4] : z4;
    float4 b1 = (n2 < N) ? *(const float4*)&W[(size_t)n2 * K + k0 + lk4] : z4;
    __syncthreads();
    As[lk4 + 0][lr] = a0.x; As[lk4 + 1][lr] = a0.y; As[lk4 + 2][lr] = a0.z; As[lk4 + 3][lr] = a0.w;
    As[lk4 + 0][lr + 32] = a1.x; As[lk4 + 1][lr + 32] = a1.y; As[lk4 + 2][lr + 32] = a1.z; As[lk4 + 3][lr + 32] = a1.w;
    Bs[lk4 + 0][lr] = b0.x; Bs[lk4 + 1][lr] = b0.y; Bs[lk4 + 2][lr] = b0.z; Bs[lk4 + 3][lr] = b0.w;
    Bs[lk4 + 0][lr + 32] = b1.x; Bs[lk4 + 1][lr + 32] = b1.y; Bs[lk4 + 2][lr + 32] = b1.z; Bs[lk4 + 3][lr + 32] = b1.w;
    __syncthreads();
    #pragma unroll
    for (int kk = 0; kk < 32; ++kk) {
      float4 av = *(const float4*)&As[kk][ty << 2];
      float4 bv = *(const float4*)&Bs[kk][tx << 2];
      acc[0][0] = fmaf(av.x, bv.x, acc[0][0]); acc[0][1] = fmaf(av.x, bv.y, acc[0][1]);
      acc[0][2] = fmaf(av.x, bv.z, acc[0][2]); acc[0][3] = fmaf(av.x, bv.w, acc[0][3]);
      acc[1][0] = fmaf(av.y, bv.x, acc[1][0]); acc[1][1] = fmaf(av.y, bv.y, acc[1][1]);
      acc[1][2] = fmaf(av.y, bv.z, acc[1][2]); acc[1][3] = fmaf(av.y, bv.w, acc[1][3]);
      acc[2][0] = fmaf(av.z, bv.x, acc[2][0]); acc[2][1] = fmaf(av.z, bv.y, acc[2][1]);
      acc[2][2] = fmaf(av.z, bv.z, acc[2][2]); acc[2][3] = fmaf(av.z, bv.w, acc[2][3]);
      acc[3][0] = fmaf(av.w, bv.x, acc[3][0]); acc[3][1] = fmaf(av.w, bv.y, acc[3][1]);
      acc[3][2] = fmaf(av.w, bv.z, acc[3][2]); acc[3][3] = fmaf(av.w, bv.w, acc[3][3]);
    }
  }
  float* Pz = P + (size_t)blockIdx.z * sliceStride;
  #pragma unroll
  for (int i = 0; i < 4; ++i) {
    int m = m0 + (ty << 2) + i;
    #pragma unroll
    for (int j = 0; j < 4; ++j) {
      int n = n0 + (tx << 2) + j;
      if (n < N) Pz[(size_t)m * N + n] = acc[i][j];
    }
  }
}

// Y[i] = bias[i%N] + sum_z P[z*stride + i]
__global__ void reduce_bias_kernel(const float* __restrict__ P,
                                   const float* __restrict__ bias,
                                   float* __restrict__ Y,
                                   int MN, int N, int S, int sliceStride) {
  int i = blockIdx.x * 256 + threadIdx.x;
  if (i >= MN) return;
  float s = bias[i % N];
  for (int z = 0; z < S; ++z) s += P[(size_t)z * sliceStride + i];
  Y[i] = s;
}

// bn + relu: xl = relu(bn(y))
__global__ void bn_relu_kernel(const float* __restrict__ X,
                               const float* __restrict__ mean, const float* __restrict__ rstd,
                               const float* __restrict__ g, const float* __restrict__ bta,
                               float* __restrict__ Y) {
  int i = blockIdx.x * 256 + threadIdx.x;
  if (i >= B_DIM * C_DIM) return;
  int c = i & 2047;
  float v = (X[i] - mean[c]) * rstd[c] * g[c] + bta[c];
  Y[i] = fmaxf(v, 0.f);
}

// fused head BN1 inputs: an_l, an_h, an_f (both halves)
__global__ void head_inputs_kernel(
    const float* __restrict__ xl, const float* __restrict__ mp,
    const float* __restrict__ mean_xl, const float* __restrict__ rstd_xl,
    const float* __restrict__ mean_mp, const float* __restrict__ rstd_mp,
    const float* __restrict__ hl_g1, const float* __restrict__ hl_b1,
    const float* __restrict__ hh_g1, const float* __restrict__ hh_b1,
    const float* __restrict__ hf_g1, const float* __restrict__ hf_b1,
    float* __restrict__ an_l, float* __restrict__ an_h, float* __restrict__ an_f) {
  int i = blockIdx.x * 256 + threadIdx.x;
  if (i >= B_DIM * C_DIM) return;
  int b = i >> 11, c = i & 2047;
  float xn = (xl[i] - mean_xl[c]) * rstd_xl[c];
  float mn = (mp[i] - mean_mp[c]) * rstd_mp[c];
  an_l[i] = xn * hl_g1[c] + hl_b1[c];
  an_h[i] = mn * hh_g1[c] + hh_b1[c];
  size_t fo = ((size_t)b << 12) + c;
  an_f[fo] = xn * hf_g1[c] + hf_b1[c];
  an_f[fo + 2048] = mn * hf_g1[2048 + c] + hf_b1[2048 + c];
}

// fused colstats over h1_l(512), h1_h(512), h1_f(1024) -> 2048 columns total
__global__ void colstats3_kernel(const float* __restrict__ h1_l, const float* __restrict__ h1_h,
                                 const float* __restrict__ h1_f,
                                 float* __restrict__ m1l, float* __restrict__ r1l,
                                 float* __restrict__ m1h, float* __restrict__ r1h,
                                 float* __restrict__ m1f, float* __restrict__ r1f) {
  int c = blockIdx.x * 256 + threadIdx.x;
  if (c >= 2048) return;
  const float* X; int N, cc; float *mo, *ro;
  if (c < 512)       { X = h1_l; N = 512;  cc = c;        mo = m1l; ro = r1l; }
  else if (c < 1024) { X = h1_h; N = 512;  cc = c - 512;  mo = m1h; ro = r1h; }
  else               { X = h1_f; N = 1024; cc = c - 1024; mo = m1f; ro = r1f; }
  float s = 0.f, q = 0.f;
  for (int b = 0; b < B_DIM; ++b) {
    float v = X[(size_t)b * N + cc];
    s += v; q += v * v;
  }
  float m = s * (1.f / B_DIM);
  float var = q * (1.f / B_DIM) - m * m;
  if (var < 0.f) var = 0.f;
  mo[cc] = m;
  ro[cc] = rsqrtf(var + 1e-5f);
}

// fused BN2+ELU for the three heads
__global__ void bn_elu3_kernel(const float* __restrict__ h1_l, const float* __restrict__ h1_h,
                               const float* __restrict__ h1_f,
                               const float* __restrict__ m1l, const float* __restrict__ r1l,
                               const float* __restrict__ m1h, const float* __restrict__ r1h,
                               const float* __restrict__ m1f, const float* __restrict__ r1f,
                               const float* __restrict__ gl, const float* __restrict__ bl,
                               const float* __restrict__ gh, const float* __restrict__ bh,
                               const float* __restrict__ gf, const float* __restrict__ bf,
                               float* __restrict__ a2_l, float* __restrict__ a2_h,
                               float* __restrict__ a2_f) {
  int i = blockIdx.x * 256 + threadIdx.x;
  if (i >= B_DIM * 2048) return;
  int b = i >> 11, c = i & 2047;
  const float* X; const float *mn, *rs, *g, *bt; float* Y; int N, cc;
  if (c < 512)       { X = h1_l; N = 512;  cc = c;        mn = m1l; rs = r1l; g = gl; bt = bl; Y = a2_l; }
  else if (c < 1024) { X = h1_h; N = 512;  cc = c - 512;  mn = m1h; rs = r1h; g = gh; bt = bh; Y = a2_h; }
  else               { X = h1_f; N = 1024; cc = c - 1024; mn = m1f; rs = r1f; g = gf; bt = bf; Y = a2_f; }
  size_t idx = (size_t)b * N + cc;
  float v = (X[idx] - mn[cc]) * rs[cc] * g[cc] + bt[cc];
  Y[idx] = v > 0.f ? v : expm1f(v);
}

// final reduce: out[0:25600]=low, [25600:51200]=high, [51200:76800]=full
__global__ void reduce_out_kernel(const float* __restrict__ P,
                                  const float* __restrict__ bl,
                                  const float* __restrict__ bh,
                                  const float* __restrict__ bf,
                                  float* __restrict__ out) {
  int i = blockIdx.x * 256 + threadIdx.x;
  if (i >= 76800) return;
  int job = i / 25600;
  int n = (i - job * 25600) % 200;
  float s = (job == 0) ? bl[n] : (job == 1) ? bh[n] : bf[n];
  for (int z = 0; z < 8; ++z) s += P[(size_t)z * 76800 + i];
  out[i] = s;
}

// ---------------------------------------------------------------------------
extern "C" void kernel_launch(void* const* d_in, const int* in_sizes, int n_in,
                              void* d_out, int out_size, void* d_ws, size_t ws_size,
                              hipStream_t stream) {
  const float* x      = (const float*)d_in[0];
  const float* g_bn_g = (const float*)d_in[1];
  const float* g_bn_b = (const float*)d_in[2];
  const float* g_w    = (const float*)d_in[3];
  const float* g_b    = (const float*)d_in[4];
  const float* e_w    = (const float*)d_in[5];
  const float* e_b    = (const float*)d_in[6];
  const float* e_g    = (const float*)d_in[7];
  const float* e_bb   = (const float*)d_in[8];
  const float* hl_g1  = (const float*)d_in[9];
  const float* hl_b1  = (const float*)d_in[10];
  const float* hl_w1  = (const float*)d_in[11];
  const float* hl_bi1 = (const float*)d_in[12];
  const float* hl_g2  = (const float*)d_in[13];
  const float* hl_b2  = (const float*)d_in[14];
  const float* hl_w2  = (const float*)d_in[15];
  const float* hl_bi2 = (const float*)d_in[16];
  const float* hh_g1  = (const float*)d_in[17];
  const float* hh_b1  = (const float*)d_in[18];
  const float* hh_w1  = (const float*)d_in[19];
  const float* hh_bi1 = (const float*)d_in[20];
  const float* hh_g2  = (const float*)d_in[21];
  const float* hh_b2  = (const float*)d_in[22];
  const float* hh_w2  = (const float*)d_in[23];
  const float* hh_bi2 = (const float*)d_in[24];
  const float* hf_g1  = (const float*)d_in[25];
  const float* hf_b1  = (const float*)d_in[26];
  const float* hf_w1  = (const float*)d_in[27];
  const float* hf_bi1 = (const float*)d_in[28];
  const float* hf_g2  = (const float*)d_in[29];
  const float* hf_b2  = (const float*)d_in[30];
  const float* hf_w2  = (const float*)d_in[31];
  const float* hf_bi2 = (const float*)d_in[32];
  float* out = (float*)d_out;

  float* W = (float*)d_ws;
  const size_t BC = (size_t)B_DIM * C_DIM;   // 262144
  float* mp   = W;                   // [128,2048]
  float* ms   = mp + BC;             // [128,2048,4]
  float* pool = ms + BC * 4;
  float* y    = pool + BC;
  float* xl   = y + BC;
  float* an_l = xl + BC;
  float* an_h = an_l + BC;
  float* an_f = an_h + BC;           // [128,4096]
  float* h1_l = an_f + BC * 2;       // [128,512]
  float* h1_h = h1_l + 128 * 512;
  float* h1_f = h1_h + 128 * 512;    // [128,1024]
  float* a2_l = h1_f + 128 * 1024;
  float* a2_h = a2_l + 128 * 512;
  float* a2_f = a2_h + 128 * 512;    // [128,1024]
  float* st   = a2_f + 128 * 1024;
  float* mean_mp = st;          float* rstd_mp = st + 2048;
  float* mean_y  = st + 4096;   float* rstd_y  = st + 6144;
  float* mean_xl = st + 8192;   float* rstd_xl = st + 10240;
  float* m1l = st + 12288;      float* r1l = st + 12800;
  float* m1h = st + 13312;      float* r1h = st + 13824;
  float* m1f = st + 14336;      float* r1f = st + 15360;
  int* sidx = (int*)(st + 16384);
  float* P_e = st + 16640;                  // 8 x 262144 (reused for w2: 8 x 76800)
  float* P_l = P_e + 8 * BC;                // 16 x 65536
  float* P_h = P_l = P_l;                   // placeholder fix below
  P_l = P_e + 8 * BC;
  float* P_l2 = P_l;
  float* P_hh = P_l + (size_t)16 * 65536;
  float* P_f  = P_hh + (size_t)16 * 65536;  // 16 x 131072
  float* P_w2 = P_e;

  // Stage A: pooling pass
  pool_max_kernel<<<65536, 256, 0, stream>>>(x, mp, ms);

  // Stage B: gate
  colstats_kernel<<<32, 256, 0, stream>>>(mp, mean_mp, rstd_mp, 2048);
  gate_kernel<<<128, 256, 0, stream>>>(mp, mean_mp, rstd_mp, g_bn_g, g_bn_b, g_w, g_b, sidx);
  pool_select_kernel<<<1024, 256, 0, stream>>>(ms, sidx, pool);

  // expert: y = pool @ e_w^T + e_b (split-K S=8, Kc=256)
  gemm_splitk_kernel<<<dim3(32, 2, 8), 256, 0, stream>>>(pool, e_w, P_e, 2048, 2048, 256, BC);
  reduce_bias_kernel<<<1024, 256, 0, stream>>>(P_e, e_b, y, BC, 2048, 8, BC);
  colstats_kernel<<<32, 256, 0, stream>>>(y, mean_y, rstd_y, 2048);
  bn_relu_kernel<<<1024, 256, 0, stream>>>(y, mean_y, rstd_y, e_g, e_bb, xl);
  colstats_kernel<<<32, 256, 0, stream>>>(xl, mean_xl, rstd_xl, 2048);

  // head BN1 inputs (fused)
  head_inputs_kernel<<<1024, 256, 0, stream>>>(xl, mp, mean_xl, rstd_xl, mean_mp, rstd_mp,
                                               hl_g1, hl_b1, hh_g1, hh_b1, hf_g1, hf_b1,
                                               an_l, an_h, an_f);

  // head linear1 (split-K)
  gemm_splitk_kernel<<<dim3(8, 2, 16), 256, 0, stream>>>(an_l, hl_w1, P_l2, 512, 2048, 128, 65536);
  gemm_splitk_kernel<<<dim3(8, 2, 16), 256, 0, stream>>>(an_h, hh_w1, P_hh, 512, 2048, 128, 65536);
  gemm_splitk_kernel<<<dim3(16, 2, 16), 256, 0, stream>>>(an_f, hf_w1, P_f, 1024, 4096, 256, 131072);
  reduce_bias_kernel<<<256, 256, 0, stream>>>(P_l2, hl_bi1, h1_l, 65536, 512, 16, 65536);
  reduce_bias_kernel<<<256, 256, 0, stream>>>(P_hh, hh_bi1, h1_h, 65536, 512, 16, 65536);
  reduce_bias_kernel<<<512, 256, 0, stream>>>(P_f, hf_bi1, h1_f, 131072, 1024, 16, 131072);

  // BN2 + ELU (fused stats + apply)
  colstats3_kernel<<<8, 256, 0, stream>>>(h1_l, h1_h, h1_f, m1l, r1l, m1h, r1h, m1f, r1f);
  bn_elu3_kernel<<<1024, 256, 0, stream>>>(h1_l, h1_h, h1_f, m1l, r1l, m1h, r1h, m1f, r1f,
                                           hl_g2, hl_b2, hh_g2, hh_b2, hf_g2, hf_b2,
                                           a2_l, a2_h, a2_f);

  // head linear2 -> grouped partials then one reduce into out
  gemm_splitk_kernel<<<dim3(4, 2, 8), 256, 0, stream>>>(a2_l, hl_w2, P_w2 + 0,     200, 512,  64,  76800);
  gemm_splitk_kernel<<<dim3(4, 2, 8), 256, 0, stream>>>(a2_h, hh_w2, P_w2 + 25600, 200, 512,  64,  76800);
  gemm_splitk_kernel<<<dim3(4, 2, 8), 256, 0, stream>>>(a2_f, hf_w2, P_w2 + 51200, 200, 1024, 128, 76800);
  reduce_out_kernel<<<300, 256, 0, stream>>>(P_w2, hl_bi2, hh_bi2, hf_bi2, out);
}

// Round 3
// 330.432 us; speedup vs baseline: 3.8726x; 1.2580x over previous
//
#include <hip/hip_runtime.h>
#include <math.h>

#define B_DIM 128
#define C_DIM 2048
#define HW2   196

// ---------------------------------------------------------------------------
// Compile-time bin descriptor tables for adaptive avg-pool scales {4,5,7,11}
// on a 14x14 tile. 211 bins total (bins OVERLAP when 14 % k != 0).
// Packed desc: rs | re<<4 | cs<<8 | ce<<12 | scale<<16. Sorted by area
// descending, dealt into 4 slots of 64 lanes -> similar trip counts per slot.
// ---------------------------------------------------------------------------
struct BinTabs { unsigned desc[256]; float inv[256]; };

static constexpr BinTabs make_tabs() {
  BinTabs t{};
  unsigned d[211] = {};
  int area[211] = {};
  int ks[4] = {4, 5, 7, 11};
  int n = 0;
  for (int s = 0; s < 4; ++s) {
    int k = ks[s];
    for (int bi = 0; bi < k; ++bi)
      for (int bj = 0; bj < k; ++bj) {
        int rs = (bi * 14) / k;
        int re = ((bi + 1) * 14 + k - 1) / k;   // ceil
        int cs = (bj * 14) / k;
        int ce = ((bj + 1) * 14 + k - 1) / k;
        d[n] = (unsigned)(rs | (re << 4) | (cs << 8) | (ce << 12) | (s << 16));
        area[n] = (re - rs) * (ce - cs);
        ++n;
      }
  }
  // insertion sort by area descending
  for (int i = 1; i < 211; ++i) {
    unsigned dv = d[i];
    int av = area[i];
    int j = i - 1;
    while (j >= 0 && area[j] < av) { d[j + 1] = d[j]; area[j + 1] = area[j]; --j; }
    d[j + 1] = dv; area[j + 1] = av;
  }
  for (int i = 0; i < 256; ++i) {
    if (i < 211) { t.desc[i] = d[i]; t.inv[i] = 1.0f / (float)area[i]; }
    else         { t.desc[i] = 0u;   t.inv[i] = 0.f; }
  }
  return t;
}

__device__ __constant__ BinTabs g_tabs = make_tabs();

// ---------------------------------------------------------------------------
// K1: per-(b,c) 14x14 tile -> global max (mp) + 4-scale pooled max (ms)
// one wave per tile; block = 4 waves; NO barrier (waves independent)
// ---------------------------------------------------------------------------
__global__ __launch_bounds__(256) void pool_max_kernel(
    const float* __restrict__ x, float* __restrict__ mp, float* __restrict__ ms) {
  __shared__ float tile[4][196];
  const int w = threadIdx.x >> 6;
  const int lane = threadIdx.x & 63;
  const size_t t = (size_t)blockIdx.x * 4 + w;
  const float* src = x + t * HW2;
  float v0 = src[lane];
  float v1 = src[64 + lane];
  float v2 = src[128 + lane];
  float v3 = -INFINITY;
  tile[w][lane] = v0;
  tile[w][64 + lane] = v1;
  tile[w][128 + lane] = v2;
  if (lane < 4) { v3 = src[192 + lane]; tile[w][192 + lane] = v3; }
  // wave-synchronous: same wave wrote tile[w]; compiler inserts lgkmcnt

  float m = fmaxf(fmaxf(v0, v1), fmaxf(v2, v3));
  #pragma unroll
  for (int off = 32; off > 0; off >>= 1) m = fmaxf(m, __shfl_xor(m, off));
  if (lane == 0) mp[t] = m;

  float smax0 = -INFINITY, smax1 = -INFINITY, smax2 = -INFINITY, smax3 = -INFINITY;
  #pragma unroll
  for (int j = 0; j < 4; ++j) {
    const int slot = (j << 6) + lane;
    const unsigned dsc = g_tabs.desc[slot];
    const float inv = g_tabs.inv[slot];
    const int rs = dsc & 15, re = (dsc >> 4) & 15;
    const int cs = (dsc >> 8) & 15, ce = (dsc >> 12) & 15;
    const int sc = (dsc >> 16) & 3;
    float s = 0.f;
    for (int r = rs; r < re; ++r) {
      const float* row = &tile[w][r * 14];
      for (int c = cs; c < ce; ++c) s += row[c];
    }
    const float val = (dsc != 0u) ? s * inv : -INFINITY;
    smax0 = (sc == 0) ? fmaxf(smax0, val) : smax0;
    smax1 = (sc == 1) ? fmaxf(smax1, val) : smax1;
    smax2 = (sc == 2) ? fmaxf(smax2, val) : smax2;
    smax3 = (sc == 3) ? fmaxf(smax3, val) : smax3;
  }
  #pragma unroll
  for (int off = 32; off > 0; off >>= 1) {
    smax0 = fmaxf(smax0, __shfl_xor(smax0, off));
    smax1 = fmaxf(smax1, __shfl_xor(smax1, off));
    smax2 = fmaxf(smax2, __shfl_xor(smax2, off));
    smax3 = fmaxf(smax3, __shfl_xor(smax3, off));
  }
  if (lane == 0) {
    float* o = ms + t * 4;
    o[0] = smax0; o[1] = smax1; o[2] = smax2; o[3] = smax3;
  }
}

// ---------------------------------------------------------------------------
// column stats over batch: mean + rsqrt(var+eps). block = 64 cols x 4 row-groups
// ---------------------------------------------------------------------------
__global__ void colstats_kernel(const float* __restrict__ X,
                                float* __restrict__ mean, float* __restrict__ rstd,
                                int N) {
  __shared__ float ss[4][64], qq[4][64];
  const int ci = threadIdx.x & 63, g = threadIdx.x >> 6;
  const int c = blockIdx.x * 64 + ci;
  float s = 0.f, q = 0.f;
  for (int b = g * 32; b < g * 32 + 32; ++b) {
    float v = X[(size_t)b * N + c];
    s += v; q += v * v;
  }
  ss[g][ci] = s; qq[g][ci] = q;
  __syncthreads();
  if (g == 0) {
    s = ss[0][ci] + ss[1][ci] + ss[2][ci] + ss[3][ci];
    q = qq[0][ci] + qq[1][ci] + qq[2][ci] + qq[3][ci];
    float m = s * (1.f / B_DIM);
    float var = q * (1.f / B_DIM) - m * m;
    if (var < 0.f) var = 0.f;
    mean[c] = m;
    rstd[c] = rsqrtf(var + 1e-5f);
  }
}

// ---------------------------------------------------------------------------
__global__ void gate_kernel(const float* __restrict__ mp,
                            const float* __restrict__ mean, const float* __restrict__ rstd,
                            const float* __restrict__ gg, const float* __restrict__ gb,
                            const float* __restrict__ gw, const float* __restrict__ gbias,
                            int* __restrict__ sidx) {
  const int b = blockIdx.x;
  const int t = threadIdx.x;
  float s0 = 0.f, s1 = 0.f, s2 = 0.f, s3 = 0.f;
  for (int c = t; c < C_DIM; c += 256) {
    float v = mp[(size_t)b * C_DIM + c];
    float xn = (v - mean[c]) * rstd[c] * gg[c] + gb[c];
    float e = xn > 0.f ? xn : expm1f(xn);
    s0 += e * gw[c];
    s1 += e * gw[C_DIM + c];
    s2 += e * gw[2 * C_DIM + c];
    s3 += e * gw[3 * C_DIM + c];
  }
  __shared__ float red[4][256];
  red[0][t] = s0; red[1][t] = s1; red[2][t] = s2; red[3][t] = s3;
  __syncthreads();
  for (int st = 128; st > 0; st >>= 1) {
    if (t < st) {
      red[0][t] += red[0][t + st];
      red[1][t] += red[1][t + st];
      red[2][t] += red[2][t + st];
      red[3][t] += red[3][t + st];
    }
    __syncthreads();
  }
  if (t == 0) {
    float best = red[0][0] + gbias[0];
    int bi = 0;
    for (int j = 1; j < 4; ++j) {
      float l = red[j][0] + gbias[j];
      if (l > best) { best = l; bi = j; }
    }
    sidx[b] = bi;
  }
}

__global__ void pool_select_kernel(const float* __restrict__ ms,
                                   const int* __restrict__ sidx,
                                   float* __restrict__ pool) {
  int i = blockIdx.x * 256 + threadIdx.x;
  if (i >= B_DIM * C_DIM) return;
  pool[i] = ms[(size_t)i * 4 + sidx[i >> 11]];
}

// ---------------------------------------------------------------------------
// split-K GEMM: P[z][m][n] partial of A[128,K(chunk z)] @ W[N,K]^T
// BM=64 BN=64 BK=32, 256 threads, 4x4 micro-tile, float4 everywhere
// ---------------------------------------------------------------------------
__global__ __launch_bounds__(256) void gemm_splitk_kernel(
    const float* __restrict__ A, const float* __restrict__ W,
    float* __restrict__ P, int N, int K, int Kc, int sliceStride) {
  __shared__ float As[32][68];
  __shared__ float Bs[32][68];
  const int t = threadIdx.x;
  const int m0 = blockIdx.y << 6;
  const int n0 = blockIdx.x << 6;
  const int kbeg = blockIdx.z * Kc;
  const int lr = t >> 3;
  const int lk4 = (t & 7) << 2;
  const int tx = t & 15, ty = t >> 4;
  float acc[4][4] = {{0.f}};
  const float4 z4 = make_float4(0.f, 0.f, 0.f, 0.f);
  for (int k0 = kbeg; k0 < kbeg + Kc; k0 += 32) {
    float4 a0 = *(const float4*)&A[(size_t)(m0 + lr) * K + k0 + lk4];
    float4 a1 = *(const float4*)&A[(size_t)(m0 + lr + 32) * K + k0 + lk4];
    int n1 = n0 + lr, n2 = n0 + lr + 32;
    float4 b0 = (n1 < N) ? *(const float4*)&W[(size_t)n1 * K + k0 + lk4] : z4;
    float4 b1 = (n2 < N) ? *(const float4*)&W[(size_t)n2 * K + k0 + lk4] : z4;
    __syncthreads();
    As[lk4 + 0][lr] = a0.x; As[lk4 + 1][lr] = a0.y; As[lk4 + 2][lr] = a0.z; As[lk4 + 3][lr] = a0.w;
    As[lk4 + 0][lr + 32] = a1.x; As[lk4 + 1][lr + 32] = a1.y; As[lk4 + 2][lr + 32] = a1.z; As[lk4 + 3][lr + 32] = a1.w;
    Bs[lk4 + 0][lr] = b0.x; Bs[lk4 + 1][lr] = b0.y; Bs[lk4 + 2][lr] = b0.z; Bs[lk4 + 3][lr] = b0.w;
    Bs[lk4 + 0][lr + 32] = b1.x; Bs[lk4 + 1][lr + 32] = b1.y; Bs[lk4 + 2][lr + 32] = b1.z; Bs[lk4 + 3][lr + 32] = b1.w;
    __syncthreads();
    #pragma unroll
    for (int kk = 0; kk < 32; ++kk) {
      float4 av = *(const float4*)&As[kk][ty << 2];
      float4 bv = *(const float4*)&Bs[kk][tx << 2];
      acc[0][0] = fmaf(av.x, bv.x, acc[0][0]); acc[0][1] = fmaf(av.x, bv.y, acc[0][1]);
      acc[0][2] = fmaf(av.x, bv.z, acc[0][2]); acc[0][3] = fmaf(av.x, bv.w, acc[0][3]);
      acc[1][0] = fmaf(av.y, bv.x, acc[1][0]); acc[1][1] = fmaf(av.y, bv.y, acc[1][1]);
      acc[1][2] = fmaf(av.y, bv.z, acc[1][2]); acc[1][3] = fmaf(av.y, bv.w, acc[1][3]);
      acc[2][0] = fmaf(av.z, bv.x, acc[2][0]); acc[2][1] = fmaf(av.z, bv.y, acc[2][1]);
      acc[2][2] = fmaf(av.z, bv.z, acc[2][2]); acc[2][3] = fmaf(av.z, bv.w, acc[2][3]);
      acc[3][0] = fmaf(av.w, bv.x, acc[3][0]); acc[3][1] = fmaf(av.w, bv.y, acc[3][1]);
      acc[3][2] = fmaf(av.w, bv.z, acc[3][2]); acc[3][3] = fmaf(av.w, bv.w, acc[3][3]);
    }
  }
  float* Pz = P + (size_t)blockIdx.z * sliceStride;
  #pragma unroll
  for (int i = 0; i < 4; ++i) {
    int m = m0 + (ty << 2) + i;
    #pragma unroll
    for (int j = 0; j < 4; ++j) {
      int n = n0 + (tx << 2) + j;
      if (n < N) Pz[(size_t)m * N + n] = acc[i][j];
    }
  }
}

__global__ void reduce_bias_kernel(const float* __restrict__ P,
                                   const float* __restrict__ bias,
                                   float* __restrict__ Y,
                                   int MN, int N, int S, int sliceStride) {
  int i = blockIdx.x * 256 + threadIdx.x;
  if (i >= MN) return;
  float s = bias[i % N];
  for (int z = 0; z < S; ++z) s += P[(size_t)z * sliceStride + i];
  Y[i] = s;
}

__global__ void bn_relu_kernel(const float* __restrict__ X,
                               const float* __restrict__ mean, const float* __restrict__ rstd,
                               const float* __restrict__ g, const float* __restrict__ bta,
                               float* __restrict__ Y) {
  int i = blockIdx.x * 256 + threadIdx.x;
  if (i >= B_DIM * C_DIM) return;
  int c = i & 2047;
  float v = (X[i] - mean[c]) * rstd[c] * g[c] + bta[c];
  Y[i] = fmaxf(v, 0.f);
}

__global__ void head_inputs_kernel(
    const float* __restrict__ xl, const float* __restrict__ mp,
    const float* __restrict__ mean_xl, const float* __restrict__ rstd_xl,
    const float* __restrict__ mean_mp, const float* __restrict__ rstd_mp,
    const float* __restrict__ hl_g1, const float* __restrict__ hl_b1,
    const float* __restrict__ hh_g1, const float* __restrict__ hh_b1,
    const float* __restrict__ hf_g1, const float* __restrict__ hf_b1,
    float* __restrict__ an_l, float* __restrict__ an_h, float* __restrict__ an_f) {
  int i = blockIdx.x * 256 + threadIdx.x;
  if (i >= B_DIM * C_DIM) return;
  int b = i >> 11, c = i & 2047;
  float xn = (xl[i] - mean_xl[c]) * rstd_xl[c];
  float mn = (mp[i] - mean_mp[c]) * rstd_mp[c];
  an_l[i] = xn * hl_g1[c] + hl_b1[c];
  an_h[i] = mn * hh_g1[c] + hh_b1[c];
  size_t fo = ((size_t)b << 12) + c;
  an_f[fo] = xn * hf_g1[c] + hf_b1[c];
  an_f[fo + 2048] = mn * hf_g1[2048 + c] + hf_b1[2048 + c];
}

__global__ void colstats3_kernel(const float* __restrict__ h1_l, const float* __restrict__ h1_h,
                                 const float* __restrict__ h1_f,
                                 float* __restrict__ m1l, float* __restrict__ r1l,
                                 float* __restrict__ m1h, float* __restrict__ r1h,
                                 float* __restrict__ m1f, float* __restrict__ r1f) {
  int c = blockIdx.x * 256 + threadIdx.x;
  if (c >= 2048) return;
  const float* X; int N, cc; float *mo, *ro;
  if (c < 512)       { X = h1_l; N = 512;  cc = c;        mo = m1l; ro = r1l; }
  else if (c < 1024) { X = h1_h; N = 512;  cc = c - 512;  mo = m1h; ro = r1h; }
  else               { X = h1_f; N = 1024; cc = c - 1024; mo = m1f; ro = r1f; }
  float s = 0.f, q = 0.f;
  for (int b = 0; b < B_DIM; ++b) {
    float v = X[(size_t)b * N + cc];
    s += v; q += v * v;
  }
  float m = s * (1.f / B_DIM);
  float var = q * (1.f / B_DIM) - m * m;
  if (var < 0.f) var = 0.f;
  mo[cc] = m;
  ro[cc] = rsqrtf(var + 1e-5f);
}

__global__ void bn_elu3_kernel(const float* __restrict__ h1_l, const float* __restrict__ h1_h,
                               const float* __restrict__ h1_f,
                               const float* __restrict__ m1l, const float* __restrict__ r1l,
                               const float* __restrict__ m1h, const float* __restrict__ r1h,
                               const float* __restrict__ m1f, const float* __restrict__ r1f,
                               const float* __restrict__ gl, const float* __restrict__ bl,
                               const float* __restrict__ gh, const float* __restrict__ bh,
                               const float* __restrict__ gf, const float* __restrict__ bf,
                               float* __restrict__ a2_l, float* __restrict__ a2_h,
                               float* __restrict__ a2_f) {
  int i = blockIdx.x * 256 + threadIdx.x;
  if (i >= B_DIM * 2048) return;
  int b = i >> 11, c = i & 2047;
  const float* X; const float *mn, *rs, *g, *bt; float* Y; int N, cc;
  if (c < 512)       { X = h1_l; N = 512;  cc = c;        mn = m1l; rs = r1l; g = gl; bt = bl; Y = a2_l; }
  else if (c < 1024) { X = h1_h; N = 512;  cc = c - 512;  mn = m1h; rs = r1h; g = gh; bt = bh; Y = a2_h; }
  else               { X = h1_f; N = 1024; cc = c - 1024; mn = m1f; rs = r1f; g = gf; bt = bf; Y = a2_f; }
  size_t idx = (size_t)b * N + cc;
  float v = (X[idx] - mn[cc]) * rs[cc] * g[cc] + bt[cc];
  Y[idx] = v > 0.f ? v : expm1f(v);
}

__global__ void reduce_out_kernel(const float* __restrict__ P,
                                  const float* __restrict__ bl,
                                  const float* __restrict__ bh,
                                  const float* __restrict__ bf,
                                  float* __restrict__ out) {
  int i = blockIdx.x * 256 + threadIdx.x;
  if (i >= 76800) return;
  int job = i / 25600;
  int n = (i - job * 25600) % 200;
  float s = (job == 0) ? bl[n] : (job == 1) ? bh[n] : bf[n];
  for (int z = 0; z < 8; ++z) s += P[(size_t)z * 76800 + i];
  out[i] = s;
}

// ---------------------------------------------------------------------------
extern "C" void kernel_launch(void* const* d_in, const int* in_sizes, int n_in,
                              void* d_out, int out_size, void* d_ws, size_t ws_size,
                              hipStream_t stream) {
  const float* x      = (const float*)d_in[0];
  const float* g_bn_g = (const float*)d_in[1];
  const float* g_bn_b = (const float*)d_in[2];
  const float* g_w    = (const float*)d_in[3];
  const float* g_b    = (const float*)d_in[4];
  const float* e_w    = (const float*)d_in[5];
  const float* e_b    = (const float*)d_in[6];
  const float* e_g    = (const float*)d_in[7];
  const float* e_bb   = (const float*)d_in[8];
  const float* hl_g1  = (const float*)d_in[9];
  const float* hl_b1  = (const float*)d_in[10];
  const float* hl_w1  = (const float*)d_in[11];
  const float* hl_bi1 = (const float*)d_in[12];
  const float* hl_g2  = (const float*)d_in[13];
  const float* hl_b2  = (const float*)d_in[14];
  const float* hl_w2  = (const float*)d_in[15];
  const float* hl_bi2 = (const float*)d_in[16];
  const float* hh_g1  = (const float*)d_in[17];
  const float* hh_b1  = (const float*)d_in[18];
  const float* hh_w1  = (const float*)d_in[19];
  const float* hh_bi1 = (const float*)d_in[20];
  const float* hh_g2  = (const float*)d_in[21];
  const float* hh_b2  = (const float*)d_in[22];
  const float* hh_w2  = (const float*)d_in[23];
  const float* hh_bi2 = (const float*)d_in[24];
  const float* hf_g1  = (const float*)d_in[25];
  const float* hf_b1  = (const float*)d_in[26];
  const float* hf_w1  = (const float*)d_in[27];
  const float* hf_bi1 = (const float*)d_in[28];
  const float* hf_g2  = (const float*)d_in[29];
  const float* hf_b2  = (const float*)d_in[30];
  const float* hf_w2  = (const float*)d_in[31];
  const float* hf_bi2 = (const float*)d_in[32];
  float* out = (float*)d_out;

  float* W = (float*)d_ws;
  const size_t BC = (size_t)B_DIM * C_DIM;
  float* mp   = W;
  float* ms   = mp + BC;
  float* pool = ms + BC * 4;
  float* y    = pool + BC;
  float* xl   = y + BC;
  float* an_l = xl + BC;
  float* an_h = an_l + BC;
  float* an_f = an_h + BC;
  float* h1_l = an_f + BC * 2;
  float* h1_h = h1_l + 128 * 512;
  float* h1_f = h1_h + 128 * 512;
  float* a2_l = h1_f + 128 * 1024;
  float* a2_h = a2_l + 128 * 512;
  float* a2_f = a2_h + 128 * 512;
  float* st   = a2_f + 128 * 1024;
  float* mean_mp = st;          float* rstd_mp = st + 2048;
  float* mean_y  = st + 4096;   float* rstd_y  = st + 6144;
  float* mean_xl = st + 8192;   float* rstd_xl = st + 10240;
  float* m1l = st + 12288;      float* r1l = st + 12800;
  float* m1h = st + 13312;      float* r1h = st + 13824;
  float* m1f = st + 14336;      float* r1f = st + 15360;
  int* sidx = (int*)(st + 16384);
  float* P_e  = st + 16640;                     // 8 x 262144 (reused for w2)
  float* P_l2 = P_e + 8 * BC;                   // 16 x 65536
  float* P_hh = P_l2 + (size_t)16 * 65536;      // 16 x 65536
  float* P_f  = P_hh + (size_t)16 * 65536;      // 16 x 131072
  float* P_w2 = P_e;

  pool_max_kernel<<<65536, 256, 0, stream>>>(x, mp, ms);

  colstats_kernel<<<32, 256, 0, stream>>>(mp, mean_mp, rstd_mp, 2048);
  gate_kernel<<<128, 256, 0, stream>>>(mp, mean_mp, rstd_mp, g_bn_g, g_bn_b, g_w, g_b, sidx);
  pool_select_kernel<<<1024, 256, 0, stream>>>(ms, sidx, pool);

  gemm_splitk_kernel<<<dim3(32, 2, 8), 256, 0, stream>>>(pool, e_w, P_e, 2048, 2048, 256, BC);
  reduce_bias_kernel<<<1024, 256, 0, stream>>>(P_e, e_b, y, BC, 2048, 8, BC);
  colstats_kernel<<<32, 256, 0, stream>>>(y, mean_y, rstd_y, 2048);
  bn_relu_kernel<<<1024, 256, 0, stream>>>(y, mean_y, rstd_y, e_g, e_bb, xl);
  colstats_kernel<<<32, 256, 0, stream>>>(xl, mean_xl, rstd_xl, 2048);

  head_inputs_kernel<<<1024, 256, 0, stream>>>(xl, mp, mean_xl, rstd_xl, mean_mp, rstd_mp,
                                               hl_g1, hl_b1, hh_g1, hh_b1, hf_g1, hf_b1,
                                               an_l, an_h, an_f);

  gemm_splitk_kernel<<<dim3(8, 2, 16), 256, 0, stream>>>(an_l, hl_w1, P_l2, 512, 2048, 128, 65536);
  gemm_splitk_kernel<<<dim3(8, 2, 16), 256, 0, stream>>>(an_h, hh_w1, P_hh, 512, 2048, 128, 65536);
  gemm_splitk_kernel<<<dim3(16, 2, 16), 256, 0, stream>>>(an_f, hf_w1, P_f, 1024, 4096, 256, 131072);
  reduce_bias_kernel<<<256, 256, 0, stream>>>(P_l2, hl_bi1, h1_l, 65536, 512, 16, 65536);
  reduce_bias_kernel<<<256, 256, 0, stream>>>(P_hh, hh_bi1, h1_h, 65536, 512, 16, 65536);
  reduce_bias_kernel<<<512, 256, 0, stream>>>(P_f, hf_bi1, h1_f, 131072, 1024, 16, 131072);

  colstats3_kernel<<<8, 256, 0, stream>>>(h1_l, h1_h, h1_f, m1l, r1l, m1h, r1h, m1f, r1f);
  bn_elu3_kernel<<<1024, 256, 0, stream>>>(h1_l, h1_h, h1_f, m1l, r1l, m1h, r1h, m1f, r1f,
                                           hl_g2, hl_b2, hh_g2, hh_b2, hf_g2, hf_b2,
                                           a2_l, a2_h, a2_f);

  gemm_splitk_kernel<<<dim3(4, 2, 8), 256, 0, stream>>>(a2_l, hl_w2, P_w2 + 0,     200, 512,  64,  76800);
  gemm_splitk_kernel<<<dim3(4, 2, 8), 256, 0, stream>>>(a2_h, hh_w2, P_w2 + 25600, 200, 512,  64,  76800);
  gemm_splitk_kernel<<<dim3(4, 2, 8), 256, 0, stream>>>(a2_f, hf_w2, P_w2 + 51200, 200, 1024, 128, 76800);
  reduce_out_kernel<<<300, 256, 0, stream>>>(P_w2, hl_bi2, hh_bi2, hf_bi2, out);
}

// Round 4
// 212.507 us; speedup vs baseline: 6.0215x; 1.5549x over previous
//
#include <hip/hip_runtime.h>
#include <math.h>

#define B_DIM 128
#define C_DIM 2048
#define HW2   196

// ---------------------------------------------------------------------------
// K1: per-(b,c) 14x14 tile -> global max (mp) + 4-scale adaptive avg-pool max.
// Lane mapping: lane = 16*g + c ; g = tile-in-wave (0..3), c = column (0..13).
// Fully register-resident separable pooling:
//   vertical prefix sum (static) -> row-interval sums (static subtracts)
//   -> column windows via shfl_down -> masked fmax -> group max reduce.
// All loop bounds / masks / areas are compile-time. No divergent loops.
// ---------------------------------------------------------------------------
__global__ __launch_bounds__(256) void pool_max_kernel(
    const float* __restrict__ x, float* __restrict__ mp, float* __restrict__ ms) {
  __shared__ float lds[4][4][208];   // [wave][tile][padded 196->208]
  const int tid  = threadIdx.x;
  const int w    = tid >> 6;
  const int lane = tid & 63;
  const int g    = lane >> 4;        // tile within wave
  const int c    = lane & 15;        // column (0..13 valid)
  const size_t waveBase = (size_t)blockIdx.x * 16 + w * 4;   // first tile of wave

  // stage 4 tiles (196 float4) into LDS, float4-coalesced
  const float* src = x + waveBase * HW2;
  #pragma unroll
  for (int j = 0; j < 4; ++j) {
    int f = lane + 64 * j;           // float4 index 0..195
    if (f < 196) {
      int t = (f * 669) >> 15;       // f / 49 (exact for f<196)
      float4 v = *(const float4*)(src + f * 4);
      *(float4*)&lds[w][t][(f - 49 * t) * 4] = v;
    }
  }
  // wave-synchronous: same wave wrote this region; compiler inserts lgkmcnt.

  // read column c of tile g (stride 14 floats; 2-way bank alias across g = free)
  float xv[14];
  const float* col = &lds[w][g][c];
  #pragma unroll
  for (int r = 0; r < 14; ++r) xv[r] = col[r * 14];

  // global max (mp): column max then 16-lane-group reduce
  float cmax = (c < 14) ? xv[0] : -INFINITY;
  #pragma unroll
  for (int r = 1; r < 14; ++r) if (c < 14) cmax = fmaxf(cmax, xv[r]);
  #pragma unroll
  for (int off = 8; off > 0; off >>= 1) cmax = fmaxf(cmax, __shfl_xor(cmax, off));

  // vertical prefix: P[r] = sum of xv[0..r-1]
  float P[15];
  P[0] = 0.f;
  #pragma unroll
  for (int r = 0; r < 14; ++r) P[r + 1] = P[r] + xv[r];

  float sm0, sm1, sm2, sm3;

  // ---- scale k=4: row/col intervals [0,4),[3,7),[7,11),[10,14); area 16 ----
  {
    constexpr int rs[4] = {0, 3, 7, 10}, re[4] = {4, 7, 11, 14};
    const bool valid = (0x489u >> c) & 1;          // starts {0,3,7,10}
    float vmax = -INFINITY;
    #pragma unroll
    for (int i = 0; i < 4; ++i) {
      float v  = P[re[i]] - P[rs[i]];
      float w2 = v + __shfl_down(v, 1);
      float w4 = w2 + __shfl_down(w2, 2);
      vmax = fmaxf(vmax, valid ? w4 : -INFINITY);
    }
    #pragma unroll
    for (int off = 8; off > 0; off >>= 1) vmax = fmaxf(vmax, __shfl_xor(vmax, off));
    sm0 = vmax * 0.0625f;                           // deferred 1/16
  }

  // ---- scale k=5: starts {0,2,5,8,11}, lens {3,4,4,4,3} ----
  {
    constexpr int rs[5] = {0, 2, 5, 8, 11}, re[5] = {3, 6, 9, 12, 14};
    constexpr float srl[5] = {1.f/3.f, 0.25f, 0.25f, 0.25f, 1.f/3.f};
    const bool valid = (0x925u >> c) & 1;          // starts {0,2,5,8,11}
    const bool is3   = (0x801u >> c) & 1;          // len-3 starts {0,11}
    const float invc = is3 ? (1.f/3.f) : 0.25f;
    float vmax = -INFINITY;
    #pragma unroll
    for (int i = 0; i < 5; ++i) {
      float v  = P[re[i]] - P[rs[i]];
      float d1 = __shfl_down(v, 1);
      float d2 = __shfl_down(v, 2);
      float w2 = v + d1;
      float w3 = w2 + d2;
      float w4 = w2 + __shfl_down(w2, 2);
      float wv = (is3 ? w3 : w4) * invc * srl[i];
      vmax = fmaxf(vmax, valid ? wv : -INFINITY);
    }
    #pragma unroll
    for (int off = 8; off > 0; off >>= 1) vmax = fmaxf(vmax, __shfl_xor(vmax, off));
    sm1 = vmax;
  }

  // ---- scale k=7: starts {0,2,4,6,8,10,12}, all len 2; area 4 ----
  {
    constexpr int rs[7] = {0, 2, 4, 6, 8, 10, 12};
    const bool valid = (0x1555u >> c) & 1;
    float vmax = -INFINITY;
    #pragma unroll
    for (int i = 0; i < 7; ++i) {
      float v  = P[rs[i] + 2] - P[rs[i]];
      float w2 = v + __shfl_down(v, 1);
      vmax = fmaxf(vmax, valid ? w2 : -INFINITY);
    }
    #pragma unroll
    for (int off = 8; off > 0; off >>= 1) vmax = fmaxf(vmax, __shfl_xor(vmax, off));
    sm2 = vmax * 0.25f;                             // deferred 1/4
  }

  // ---- scale k=11: starts {0,1,2,3,5,6,7,8,10,11,12}, lens {2,2,2,3,2,2,2,3,2,2,2} ----
  {
    constexpr int rs[11] = {0, 1, 2, 3, 5, 6, 7, 8, 10, 11, 12};
    constexpr int re[11] = {2, 3, 4, 6, 7, 8, 9, 11, 12, 13, 14};
    constexpr float srl[11] = {0.5f, 0.5f, 0.5f, 1.f/3.f, 0.5f, 0.5f, 0.5f,
                               1.f/3.f, 0.5f, 0.5f, 0.5f};
    const bool valid = (0x1DEFu >> c) & 1;
    const bool is3   = (0x108u >> c) & 1;          // len-3 col starts {3,8}
    const float invc = is3 ? (1.f/3.f) : 0.5f;
    float vmax = -INFINITY;
    #pragma unroll
    for (int i = 0; i < 11; ++i) {
      float v  = P[re[i]] - P[rs[i]];
      float d1 = __shfl_down(v, 1);
      float d2 = __shfl_down(v, 2);
      float w2 = v + d1;
      float w3 = w2 + d2;
      float wv = (is3 ? w3 : w2) * invc * srl[i];
      vmax = fmaxf(vmax, valid ? wv : -INFINITY);
    }
    #pragma unroll
    for (int off = 8; off > 0; off >>= 1) vmax = fmaxf(vmax, __shfl_xor(vmax, off));
    sm3 = vmax;
  }

  if (c == 0) {
    size_t T = waveBase + g;
    mp[T] = cmax;
    *(float4*)&ms[T * 4] = make_float4(sm0, sm1, sm2, sm3);
  }
}

// ---------------------------------------------------------------------------
// column stats over batch: mean + rsqrt(var+eps). block = 64 cols x 4 row-groups
// ---------------------------------------------------------------------------
__global__ void colstats_kernel(const float* __restrict__ X,
                                float* __restrict__ mean, float* __restrict__ rstd,
                                int N) {
  __shared__ float ss[4][64], qq[4][64];
  const int ci = threadIdx.x & 63, g = threadIdx.x >> 6;
  const int c = blockIdx.x * 64 + ci;
  float s = 0.f, q = 0.f;
  for (int b = g * 32; b < g * 32 + 32; ++b) {
    float v = X[(size_t)b * N + c];
    s += v; q += v * v;
  }
  ss[g][ci] = s; qq[g][ci] = q;
  __syncthreads();
  if (g == 0) {
    s = ss[0][ci] + ss[1][ci] + ss[2][ci] + ss[3][ci];
    q = qq[0][ci] + qq[1][ci] + qq[2][ci] + qq[3][ci];
    float m = s * (1.f / B_DIM);
    float var = q * (1.f / B_DIM) - m * m;
    if (var < 0.f) var = 0.f;
    mean[c] = m;
    rstd[c] = rsqrtf(var + 1e-5f);
  }
}

// ---------------------------------------------------------------------------
__global__ void gate_kernel(const float* __restrict__ mp,
                            const float* __restrict__ mean, const float* __restrict__ rstd,
                            const float* __restrict__ gg, const float* __restrict__ gb,
                            const float* __restrict__ gw, const float* __restrict__ gbias,
                            int* __restrict__ sidx) {
  const int b = blockIdx.x;
  const int t = threadIdx.x;
  float s0 = 0.f, s1 = 0.f, s2 = 0.f, s3 = 0.f;
  for (int c = t; c < C_DIM; c += 256) {
    float v = mp[(size_t)b * C_DIM + c];
    float xn = (v - mean[c]) * rstd[c] * gg[c] + gb[c];
    float e = xn > 0.f ? xn : expm1f(xn);
    s0 += e * gw[c];
    s1 += e * gw[C_DIM + c];
    s2 += e * gw[2 * C_DIM + c];
    s3 += e * gw[3 * C_DIM + c];
  }
  __shared__ float red[4][256];
  red[0][t] = s0; red[1][t] = s1; red[2][t] = s2; red[3][t] = s3;
  __syncthreads();
  for (int st = 128; st > 0; st >>= 1) {
    if (t < st) {
      red[0][t] += red[0][t + st];
      red[1][t] += red[1][t + st];
      red[2][t] += red[2][t + st];
      red[3][t] += red[3][t + st];
    }
    __syncthreads();
  }
  if (t == 0) {
    float best = red[0][0] + gbias[0];
    int bi = 0;
    for (int j = 1; j < 4; ++j) {
      float l = red[j][0] + gbias[j];
      if (l > best) { best = l; bi = j; }
    }
    sidx[b] = bi;
  }
}

__global__ void pool_select_kernel(const float* __restrict__ ms,
                                   const int* __restrict__ sidx,
                                   float* __restrict__ pool) {
  int i = blockIdx.x * 256 + threadIdx.x;
  if (i >= B_DIM * C_DIM) return;
  pool[i] = ms[(size_t)i * 4 + sidx[i >> 11]];
}

// ---------------------------------------------------------------------------
// split-K GEMM: P[z][m][n] partial of A[128,K(chunk z)] @ W[N,K]^T
// BM=64 BN=64 BK=32, 256 threads, 4x4 micro-tile, float4 everywhere
// ---------------------------------------------------------------------------
__global__ __launch_bounds__(256) void gemm_splitk_kernel(
    const float* __restrict__ A, const float* __restrict__ W,
    float* __restrict__ P, int N, int K, int Kc, int sliceStride) {
  __shared__ float As[32][68];
  __shared__ float Bs[32][68];
  const int t = threadIdx.x;
  const int m0 = blockIdx.y << 6;
  const int n0 = blockIdx.x << 6;
  const int kbeg = blockIdx.z * Kc;
  const int lr = t >> 3;
  const int lk4 = (t & 7) << 2;
  const int tx = t & 15, ty = t >> 4;
  float acc[4][4] = {{0.f}};
  const float4 z4 = make_float4(0.f, 0.f, 0.f, 0.f);
  for (int k0 = kbeg; k0 < kbeg + Kc; k0 += 32) {
    float4 a0 = *(const float4*)&A[(size_t)(m0 + lr) * K + k0 + lk4];
    float4 a1 = *(const float4*)&A[(size_t)(m0 + lr + 32) * K + k0 + lk4];
    int n1 = n0 + lr, n2 = n0 + lr + 32;
    float4 b0 = (n1 < N) ? *(const float4*)&W[(size_t)n1 * K + k0 + lk4] : z4;
    float4 b1 = (n2 < N) ? *(const float4*)&W[(size_t)n2 * K + k0 + lk4] : z4;
    __syncthreads();
    As[lk4 + 0][lr] = a0.x; As[lk4 + 1][lr] = a0.y; As[lk4 + 2][lr] = a0.z; As[lk4 + 3][lr] = a0.w;
    As[lk4 + 0][lr + 32] = a1.x; As[lk4 + 1][lr + 32] = a1.y; As[lk4 + 2][lr + 32] = a1.z; As[lk4 + 3][lr + 32] = a1.w;
    Bs[lk4 + 0][lr] = b0.x; Bs[lk4 + 1][lr] = b0.y; Bs[lk4 + 2][lr] = b0.z; Bs[lk4 + 3][lr] = b0.w;
    Bs[lk4 + 0][lr + 32] = b1.x; Bs[lk4 + 1][lr + 32] = b1.y; Bs[lk4 + 2][lr + 32] = b1.z; Bs[lk4 + 3][lr + 32] = b1.w;
    __syncthreads();
    #pragma unroll
    for (int kk = 0; kk < 32; ++kk) {
      float4 av = *(const float4*)&As[kk][ty << 2];
      float4 bv = *(const float4*)&Bs[kk][tx << 2];
      acc[0][0] = fmaf(av.x, bv.x, acc[0][0]); acc[0][1] = fmaf(av.x, bv.y, acc[0][1]);
      acc[0][2] = fmaf(av.x, bv.z, acc[0][2]); acc[0][3] = fmaf(av.x, bv.w, acc[0][3]);
      acc[1][0] = fmaf(av.y, bv.x, acc[1][0]); acc[1][1] = fmaf(av.y, bv.y, acc[1][1]);
      acc[1][2] = fmaf(av.y, bv.z, acc[1][2]); acc[1][3] = fmaf(av.y, bv.w, acc[1][3]);
      acc[2][0] = fmaf(av.z, bv.x, acc[2][0]); acc[2][1] = fmaf(av.z, bv.y, acc[2][1]);
      acc[2][2] = fmaf(av.z, bv.z, acc[2][2]); acc[2][3] = fmaf(av.z, bv.w, acc[2][3]);
      acc[3][0] = fmaf(av.w, bv.x, acc[3][0]); acc[3][1] = fmaf(av.w, bv.y, acc[3][1]);
      acc[3][2] = fmaf(av.w, bv.z, acc[3][2]); acc[3][3] = fmaf(av.w, bv.w, acc[3][3]);
    }
  }
  float* Pz = P + (size_t)blockIdx.z * sliceStride;
  #pragma unroll
  for (int i = 0; i < 4; ++i) {
    int m = m0 + (ty << 2) + i;
    #pragma unroll
    for (int j = 0; j < 4; ++j) {
      int n = n0 + (tx << 2) + j;
      if (n < N) Pz[(size_t)m * N + n] = acc[i][j];
    }
  }
}

__global__ void reduce_bias_kernel(const float* __restrict__ P,
                                   const float* __restrict__ bias,
                                   float* __restrict__ Y,
                                   int MN, int N, int S, int sliceStride) {
  int i = blockIdx.x * 256 + threadIdx.x;
  if (i >= MN) return;
  float s = bias[i % N];
  for (int z = 0; z < S; ++z) s += P[(size_t)z * sliceStride + i];
  Y[i] = s;
}

__global__ void bn_relu_kernel(const float* __restrict__ X,
                               const float* __restrict__ mean, const float* __restrict__ rstd,
                               const float* __restrict__ g, const float* __restrict__ bta,
                               float* __restrict__ Y) {
  int i = blockIdx.x * 256 + threadIdx.x;
  if (i >= B_DIM * C_DIM) return;
  int c = i & 2047;
  float v = (X[i] - mean[c]) * rstd[c] * g[c] + bta[c];
  Y[i] = fmaxf(v, 0.f);
}

__global__ void head_inputs_kernel(
    const float* __restrict__ xl, const float* __restrict__ mp,
    const float* __restrict__ mean_xl, const float* __restrict__ rstd_xl,
    const float* __restrict__ mean_mp, const float* __restrict__ rstd_mp,
    const float* __restrict__ hl_g1, const float* __restrict__ hl_b1,
    const float* __restrict__ hh_g1, const float* __restrict__ hh_b1,
    const float* __restrict__ hf_g1, const float* __restrict__ hf_b1,
    float* __restrict__ an_l, float* __restrict__ an_h, float* __restrict__ an_f) {
  int i = blockIdx.x * 256 + threadIdx.x;
  if (i >= B_DIM * C_DIM) return;
  int b = i >> 11, c = i & 2047;
  float xn = (xl[i] - mean_xl[c]) * rstd_xl[c];
  float mn = (mp[i] - mean_mp[c]) * rstd_mp[c];
  an_l[i] = xn * hl_g1[c] + hl_b1[c];
  an_h[i] = mn * hh_g1[c] + hh_b1[c];
  size_t fo = ((size_t)b << 12) + c;
  an_f[fo] = xn * hf_g1[c] + hf_b1[c];
  an_f[fo + 2048] = mn * hf_g1[2048 + c] + hf_b1[2048 + c];
}

__global__ void colstats3_kernel(const float* __restrict__ h1_l, const float* __restrict__ h1_h,
                                 const float* __restrict__ h1_f,
                                 float* __restrict__ m1l, float* __restrict__ r1l,
                                 float* __restrict__ m1h, float* __restrict__ r1h,
                                 float* __restrict__ m1f, float* __restrict__ r1f) {
  int c = blockIdx.x * 256 + threadIdx.x;
  if (c >= 2048) return;
  const float* X; int N, cc; float *mo, *ro;
  if (c < 512)       { X = h1_l; N = 512;  cc = c;        mo = m1l; ro = r1l; }
  else if (c < 1024) { X = h1_h; N = 512;  cc = c - 512;  mo = m1h; ro = r1h; }
  else               { X = h1_f; N = 1024; cc = c - 1024; mo = m1f; ro = r1f; }
  float s = 0.f, q = 0.f;
  for (int b = 0; b < B_DIM; ++b) {
    float v = X[(size_t)b * N + cc];
    s += v; q += v * v;
  }
  float m = s * (1.f / B_DIM);
  float var = q * (1.f / B_DIM) - m * m;
  if (var < 0.f) var = 0.f;
  mo[cc] = m;
  ro[cc] = rsqrtf(var + 1e-5f);
}

__global__ void bn_elu3_kernel(const float* __restrict__ h1_l, const float* __restrict__ h1_h,
                               const float* __restrict__ h1_f,
                               const float* __restrict__ m1l, const float* __restrict__ r1l,
                               const float* __restrict__ m1h, const float* __restrict__ r1h,
                               const float* __restrict__ m1f, const float* __restrict__ r1f,
                               const float* __restrict__ gl, const float* __restrict__ bl,
                               const float* __restrict__ gh, const float* __restrict__ bh,
                               const float* __restrict__ gf, const float* __restrict__ bf,
                               float* __restrict__ a2_l, float* __restrict__ a2_h,
                               float* __restrict__ a2_f) {
  int i = blockIdx.x * 256 + threadIdx.x;
  if (i >= B_DIM * 2048) return;
  int b = i >> 11, c = i & 2047;
  const float* X; const float *mn, *rs, *g, *bt; float* Y; int N, cc;
  if (c < 512)       { X = h1_l; N = 512;  cc = c;        mn = m1l; rs = r1l; g = gl; bt = bl; Y = a2_l; }
  else if (c < 1024) { X = h1_h; N = 512;  cc = c - 512;  mn = m1h; rs = r1h; g = gh; bt = bh; Y = a2_h; }
  else               { X = h1_f; N = 1024; cc = c - 1024; mn = m1f; rs = r1f; g = gf; bt = bf; Y = a2_f; }
  size_t idx = (size_t)b * N + cc;
  float v = (X[idx] - mn[cc]) * rs[cc] * g[cc] + bt[cc];
  Y[idx] = v > 0.f ? v : expm1f(v);
}

__global__ void reduce_out_kernel(const float* __restrict__ P,
                                  const float* __restrict__ bl,
                                  const float* __restrict__ bh,
                                  const float* __restrict__ bf,
                                  float* __restrict__ out) {
  int i = blockIdx.x * 256 + threadIdx.x;
  if (i >= 76800) return;
  int job = i / 25600;
  int n = (i - job * 25600) % 200;
  float s = (job == 0) ? bl[n] : (job == 1) ? bh[n] : bf[n];
  for (int z = 0; z < 8; ++z) s += P[(size_t)z * 76800 + i];
  out[i] = s;
}

// ---------------------------------------------------------------------------
extern "C" void kernel_launch(void* const* d_in, const int* in_sizes, int n_in,
                              void* d_out, int out_size, void* d_ws, size_t ws_size,
                              hipStream_t stream) {
  const float* x      = (const float*)d_in[0];
  const float* g_bn_g = (const float*)d_in[1];
  const float* g_bn_b = (const float*)d_in[2];
  const float* g_w    = (const float*)d_in[3];
  const float* g_b    = (const float*)d_in[4];
  const float* e_w    = (const float*)d_in[5];
  const float* e_b    = (const float*)d_in[6];
  const float* e_g    = (const float*)d_in[7];
  const float* e_bb   = (const float*)d_in[8];
  const float* hl_g1  = (const float*)d_in[9];
  const float* hl_b1  = (const float*)d_in[10];
  const float* hl_w1  = (const float*)d_in[11];
  const float* hl_bi1 = (const float*)d_in[12];
  const float* hl_g2  = (const float*)d_in[13];
  const float* hl_b2  = (const float*)d_in[14];
  const float* hl_w2  = (const float*)d_in[15];
  const float* hl_bi2 = (const float*)d_in[16];
  const float* hh_g1  = (const float*)d_in[17];
  const float* hh_b1  = (const float*)d_in[18];
  const float* hh_w1  = (const float*)d_in[19];
  const float* hh_bi1 = (const float*)d_in[20];
  const float* hh_g2  = (const float*)d_in[21];
  const float* hh_b2  = (const float*)d_in[22];
  const float* hh_w2  = (const float*)d_in[23];
  const float* hh_bi2 = (const float*)d_in[24];
  const float* hf_g1  = (const float*)d_in[25];
  const float* hf_b1  = (const float*)d_in[26];
  const float* hf_w1  = (const float*)d_in[27];
  const float* hf_bi1 = (const float*)d_in[28];
  const float* hf_g2  = (const float*)d_in[29];
  const float* hf_b2  = (const float*)d_in[30];
  const float* hf_w2  = (const float*)d_in[31];
  const float* hf_bi2 = (const float*)d_in[32];
  float* out = (float*)d_out;

  float* W = (float*)d_ws;
  const size_t BC = (size_t)B_DIM * C_DIM;
  float* mp   = W;
  float* ms   = mp + BC;
  float* pool = ms + BC * 4;
  float* y    = pool + BC;
  float* xl   = y + BC;
  float* an_l = xl + BC;
  float* an_h = an_l + BC;
  float* an_f = an_h + BC;
  float* h1_l = an_f + BC * 2;
  float* h1_h = h1_l + 128 * 512;
  float* h1_f = h1_h + 128 * 512;
  float* a2_l = h1_f + 128 * 1024;
  float* a2_h = a2_l + 128 * 512;
  float* a2_f = a2_h + 128 * 512;
  float* st   = a2_f + 128 * 1024;
  float* mean_mp = st;          float* rstd_mp = st + 2048;
  float* mean_y  = st + 4096;   float* rstd_y  = st + 6144;
  float* mean_xl = st + 8192;   float* rstd_xl = st + 10240;
  float* m1l = st + 12288;      float* r1l = st + 12800;
  float* m1h = st + 13312;      float* r1h = st + 13824;
  float* m1f = st + 14336;      float* r1f = st + 15360;
  int* sidx = (int*)(st + 16384);
  float* P_e  = st + 16640;                     // 8 x 262144 (reused for w2)
  float* P_l2 = P_e + 8 * BC;                   // 16 x 65536
  float* P_hh = P_l2 + (size_t)16 * 65536;      // 16 x 65536
  float* P_f  = P_hh + (size_t)16 * 65536;      // 16 x 131072
  float* P_w2 = P_e;

  pool_max_kernel<<<16384, 256, 0, stream>>>(x, mp, ms);

  colstats_kernel<<<32, 256, 0, stream>>>(mp, mean_mp, rstd_mp, 2048);
  gate_kernel<<<128, 256, 0, stream>>>(mp, mean_mp, rstd_mp, g_bn_g, g_bn_b, g_w, g_b, sidx);
  pool_select_kernel<<<1024, 256, 0, stream>>>(ms, sidx, pool);

  gemm_splitk_kernel<<<dim3(32, 2, 8), 256, 0, stream>>>(pool, e_w, P_e, 2048, 2048, 256, BC);
  reduce_bias_kernel<<<1024, 256, 0, stream>>>(P_e, e_b, y, BC, 2048, 8, BC);
  colstats_kernel<<<32, 256, 0, stream>>>(y, mean_y, rstd_y, 2048);
  bn_relu_kernel<<<1024, 256, 0, stream>>>(y, mean_y, rstd_y, e_g, e_bb, xl);
  colstats_kernel<<<32, 256, 0, stream>>>(xl, mean_xl, rstd_xl, 2048);

  head_inputs_kernel<<<1024, 256, 0, stream>>>(xl, mp, mean_xl, rstd_xl, mean_mp, rstd_mp,
                                               hl_g1, hl_b1, hh_g1, hh_b1, hf_g1, hf_b1,
                                               an_l, an_h, an_f);

  gemm_splitk_kernel<<<dim3(8, 2, 16), 256, 0, stream>>>(an_l, hl_w1, P_l2, 512, 2048, 128, 65536);
  gemm_splitk_kernel<<<dim3(8, 2, 16), 256, 0, stream>>>(an_h, hh_w1, P_hh, 512, 2048, 128, 65536);
  gemm_splitk_kernel<<<dim3(16, 2, 16), 256, 0, stream>>>(an_f, hf_w1, P_f, 1024, 4096, 256, 131072);
  reduce_bias_kernel<<<256, 256, 0, stream>>>(P_l2, hl_bi1, h1_l, 65536, 512, 16, 65536);
  reduce_bias_kernel<<<256, 256, 0, stream>>>(P_hh, hh_bi1, h1_h, 65536, 512, 16, 65536);
  reduce_bias_kernel<<<512, 256, 0, stream>>>(P_f, hf_bi1, h1_f, 131072, 1024, 16, 131072);

  colstats3_kernel<<<8, 256, 0, stream>>>(h1_l, h1_h, h1_f, m1l, r1l, m1h, r1h, m1f, r1f);
  bn_elu3_kernel<<<1024, 256, 0, stream>>>(h1_l, h1_h, h1_f, m1l, r1l, m1h, r1h, m1f, r1f,
                                           hl_g2, hl_b2, hh_g2, hh_b2, hf_g2, hf_b2,
                                           a2_l, a2_h, a2_f);

  gemm_splitk_kernel<<<dim3(4, 2, 8), 256, 0, stream>>>(a2_l, hl_w2, P_w2 + 0,     200, 512,  64,  76800);
  gemm_splitk_kernel<<<dim3(4, 2, 8), 256, 0, stream>>>(a2_h, hh_w2, P_w2 + 25600, 200, 512,  64,  76800);
  gemm_splitk_kernel<<<dim3(4, 2, 8), 256, 0, stream>>>(a2_f, hf_w2, P_w2 + 51200, 200, 1024, 128, 76800);
  reduce_out_kernel<<<300, 256, 0, stream>>>(P_w2, hl_bi2, hh_bi2, hf_bi2, out);
}

// Round 5
// 158.554 us; speedup vs baseline: 8.0705x; 1.3403x over previous
//
#include <hip/hip_runtime.h>
#include <math.h>

#define B_DIM 128
#define C_DIM 2048
#define HW2   196

// ---------------------------------------------------------------------------
// K1: per-(b,c) 14x14 tile -> global max (mp) + 4-scale adaptive avg-pool max.
// Lane mapping: lane = 16*g + c ; g = tile-in-wave (0..3), c = column (0..13).
// Register-resident separable pooling; all bounds/masks compile-time.
// ---------------------------------------------------------------------------
__global__ __launch_bounds__(256) void pool_max_kernel(
    const float* __restrict__ x, float* __restrict__ mp, float* __restrict__ ms) {
  __shared__ float lds[4][4][208];
  const int tid  = threadIdx.x;
  const int w    = tid >> 6;
  const int lane = tid & 63;
  const int g    = lane >> 4;
  const int c    = lane & 15;
  const size_t waveBase = (size_t)blockIdx.x * 16 + w * 4;

  const float* src = x + waveBase * HW2;
  #pragma unroll
  for (int j = 0; j < 4; ++j) {
    int f = lane + 64 * j;
    if (f < 196) {
      int t = (f * 669) >> 15;       // f / 49
      float4 v = *(const float4*)(src + f * 4);
      *(float4*)&lds[w][t][(f - 49 * t) * 4] = v;
    }
  }

  float xv[14];
  const float* col = &lds[w][g][c];
  #pragma unroll
  for (int r = 0; r < 14; ++r) xv[r] = col[r * 14];

  float cmax = (c < 14) ? xv[0] : -INFINITY;
  #pragma unroll
  for (int r = 1; r < 14; ++r) if (c < 14) cmax = fmaxf(cmax, xv[r]);
  #pragma unroll
  for (int off = 8; off > 0; off >>= 1) cmax = fmaxf(cmax, __shfl_xor(cmax, off));

  float P[15];
  P[0] = 0.f;
  #pragma unroll
  for (int r = 0; r < 14; ++r) P[r + 1] = P[r] + xv[r];

  float sm0, sm1, sm2, sm3;

  { // k=4
    constexpr int rs[4] = {0, 3, 7, 10}, re[4] = {4, 7, 11, 14};
    const bool valid = (0x489u >> c) & 1;
    float vmax = -INFINITY;
    #pragma unroll
    for (int i = 0; i < 4; ++i) {
      float v  = P[re[i]] - P[rs[i]];
      float w2 = v + __shfl_down(v, 1);
      float w4 = w2 + __shfl_down(w2, 2);
      vmax = fmaxf(vmax, valid ? w4 : -INFINITY);
    }
    #pragma unroll
    for (int off = 8; off > 0; off >>= 1) vmax = fmaxf(vmax, __shfl_xor(vmax, off));
    sm0 = vmax * 0.0625f;
  }
  { // k=5
    constexpr int rs[5] = {0, 2, 5, 8, 11}, re[5] = {3, 6, 9, 12, 14};
    constexpr float srl[5] = {1.f/3.f, 0.25f, 0.25f, 0.25f, 1.f/3.f};
    const bool valid = (0x925u >> c) & 1;
    const bool is3   = (0x801u >> c) & 1;
    const float invc = is3 ? (1.f/3.f) : 0.25f;
    float vmax = -INFINITY;
    #pragma unroll
    for (int i = 0; i < 5; ++i) {
      float v  = P[re[i]] - P[rs[i]];
      float d1 = __shfl_down(v, 1);
      float d2 = __shfl_down(v, 2);
      float w2 = v + d1;
      float w3 = w2 + d2;
      float w4 = w2 + __shfl_down(w2, 2);
      float wv = (is3 ? w3 : w4) * invc * srl[i];
      vmax = fmaxf(vmax, valid ? wv : -INFINITY);
    }
    #pragma unroll
    for (int off = 8; off > 0; off >>= 1) vmax = fmaxf(vmax, __shfl_xor(vmax, off));
    sm1 = vmax;
  }
  { // k=7
    constexpr int rs[7] = {0, 2, 4, 6, 8, 10, 12};
    const bool valid = (0x1555u >> c) & 1;
    float vmax = -INFINITY;
    #pragma unroll
    for (int i = 0; i < 7; ++i) {
      float v  = P[rs[i] + 2] - P[rs[i]];
      float w2 = v + __shfl_down(v, 1);
      vmax = fmaxf(vmax, valid ? w2 : -INFINITY);
    }
    #pragma unroll
    for (int off = 8; off > 0; off >>= 1) vmax = fmaxf(vmax, __shfl_xor(vmax, off));
    sm2 = vmax * 0.25f;
  }
  { // k=11
    constexpr int rs[11] = {0, 1, 2, 3, 5, 6, 7, 8, 10, 11, 12};
    constexpr int re[11] = {2, 3, 4, 6, 7, 8, 9, 11, 12, 13, 14};
    constexpr float srl[11] = {0.5f, 0.5f, 0.5f, 1.f/3.f, 0.5f, 0.5f, 0.5f,
                               1.f/3.f, 0.5f, 0.5f, 0.5f};
    const bool valid = (0x1DEFu >> c) & 1;
    const bool is3   = (0x108u >> c) & 1;
    const float invc = is3 ? (1.f/3.f) : 0.5f;
    float vmax = -INFINITY;
    #pragma unroll
    for (int i = 0; i < 11; ++i) {
      float v  = P[re[i]] - P[rs[i]];
      float d1 = __shfl_down(v, 1);
      float d2 = __shfl_down(v, 2);
      float w2 = v + d1;
      float w3 = w2 + d2;
      float wv = (is3 ? w3 : w2) * invc * srl[i];
      vmax = fmaxf(vmax, valid ? wv : -INFINITY);
    }
    #pragma unroll
    for (int off = 8; off > 0; off >>= 1) vmax = fmaxf(vmax, __shfl_xor(vmax, off));
    sm3 = vmax;
  }

  if (c == 0) {
    size_t T = waveBase + g;
    mp[T] = cmax;
    *(float4*)&ms[T * 4] = make_float4(sm0, sm1, sm2, sm3);
  }
}

// ---------------------------------------------------------------------------
// K2: mp column stats + affine params for hh head and hf second half.
// 128 blocks x (16 cols x 16 rowgroups of 8). s = rstd*g1; t = b1 - mean*s.
// ---------------------------------------------------------------------------
__global__ __launch_bounds__(256) void statsmp_kernel(
    const float* __restrict__ mp,
    const float* __restrict__ hh_g1, const float* __restrict__ hh_b1,
    const float* __restrict__ hf_g1, const float* __restrict__ hf_b1,
    float* __restrict__ mean_mp, float* __restrict__ rstd_mp,
    float* __restrict__ s_h, float* __restrict__ t_h,
    float* __restrict__ sf2, float* __restrict__ tf2) {
  const int ci = threadIdx.x & 15;
  const int g  = threadIdx.x >> 4;
  const int c  = blockIdx.x * 16 + ci;
  float s = 0.f, q = 0.f;
  #pragma unroll
  for (int r = 0; r < 8; ++r) {
    float v = mp[(size_t)(g * 8 + r) * C_DIM + c];
    s += v; q += v * v;
  }
  __shared__ float ss[16][16], qq[16][16];
  ss[g][ci] = s; qq[g][ci] = q;
  __syncthreads();
  if (g == 0) {
    float S = 0.f, Q = 0.f;
    #pragma unroll
    for (int j = 0; j < 16; ++j) { S += ss[j][ci]; Q += qq[j][ci]; }
    float m = S * (1.f / B_DIM);
    float var = Q * (1.f / B_DIM) - m * m;
    if (var < 0.f) var = 0.f;
    float r = rsqrtf(var + 1e-5f);
    mean_mp[c] = m; rstd_mp[c] = r;
    float a = r * hh_g1[c];        s_h[c] = a; t_h[c] = hh_b1[c] - m * a;
    float b = r * hf_g1[2048 + c]; sf2[c] = b; tf2[c] = hf_b1[2048 + c] - m * b;
  }
}

// ---------------------------------------------------------------------------
// K3: gate (BN+ELU+linear+argmax) fused with gated scale select -> pool
// ---------------------------------------------------------------------------
__global__ void gate_select_kernel(
    const float* __restrict__ mp,
    const float* __restrict__ mean, const float* __restrict__ rstd,
    const float* __restrict__ gg, const float* __restrict__ gb,
    const float* __restrict__ gw, const float* __restrict__ gbias,
    const float* __restrict__ ms, float* __restrict__ pool) {
  const int b = blockIdx.x;
  const int t = threadIdx.x;
  float s0 = 0.f, s1 = 0.f, s2 = 0.f, s3 = 0.f;
  for (int c = t; c < C_DIM; c += 256) {
    float v = mp[(size_t)b * C_DIM + c];
    float xn = (v - mean[c]) * rstd[c] * gg[c] + gb[c];
    float e = xn > 0.f ? xn : expm1f(xn);
    s0 += e * gw[c];
    s1 += e * gw[C_DIM + c];
    s2 += e * gw[2 * C_DIM + c];
    s3 += e * gw[3 * C_DIM + c];
  }
  __shared__ float red[4][256];
  __shared__ int ssel;
  red[0][t] = s0; red[1][t] = s1; red[2][t] = s2; red[3][t] = s3;
  __syncthreads();
  for (int st = 128; st > 0; st >>= 1) {
    if (t < st) {
      red[0][t] += red[0][t + st];
      red[1][t] += red[1][t + st];
      red[2][t] += red[2][t + st];
      red[3][t] += red[3][t + st];
    }
    __syncthreads();
  }
  if (t == 0) {
    float best = red[0][0] + gbias[0];
    int bi = 0;
    for (int j = 1; j < 4; ++j) {
      float l = red[j][0] + gbias[j];
      if (l > best) { best = l; bi = j; }
    }
    ssel = bi;
  }
  __syncthreads();
  const int sel = ssel;
  for (int c = t; c < C_DIM; c += 256)
    pool[(size_t)b * C_DIM + c] = ms[((size_t)b * C_DIM + c) * 4 + sel];
}

// ---------------------------------------------------------------------------
// K4: expert split-K GEMM (plain): P[z] += pool[128,Kc-chunk] @ e_w^T tile
// BM=64 BN=64 BK=32, 4x4 micro-tile
// ---------------------------------------------------------------------------
__global__ __launch_bounds__(256) void gemm_e_kernel(
    const float* __restrict__ A, const float* __restrict__ W,
    float* __restrict__ P) {
  __shared__ float As[32][68];
  __shared__ float Bs[32][68];
  const int t = threadIdx.x;
  const int m0 = blockIdx.y << 6;
  const int n0 = blockIdx.x << 6;
  const int kbeg = blockIdx.z << 8;                 // Kc = 256
  const int lr = t >> 3;
  const int lk4 = (t & 7) << 2;
  const int tx = t & 15, ty = t >> 4;
  float acc[4][4] = {{0.f}};
  for (int k0 = kbeg; k0 < kbeg + 256; k0 += 32) {
    float4 a0 = *(const float4*)&A[(size_t)(m0 + lr) * 2048 + k0 + lk4];
    float4 a1 = *(const float4*)&A[(size_t)(m0 + lr + 32) * 2048 + k0 + lk4];
    float4 b0 = *(const float4*)&W[(size_t)(n0 + lr) * 2048 + k0 + lk4];
    float4 b1 = *(const float4*)&W[(size_t)(n0 + lr + 32) * 2048 + k0 + lk4];
    __syncthreads();
    As[lk4 + 0][lr] = a0.x; As[lk4 + 1][lr] = a0.y; As[lk4 + 2][lr] = a0.z; As[lk4 + 3][lr] = a0.w;
    As[lk4 + 0][lr + 32] = a1.x; As[lk4 + 1][lr + 32] = a1.y; As[lk4 + 2][lr + 32] = a1.z; As[lk4 + 3][lr + 32] = a1.w;
    Bs[lk4 + 0][lr] = b0.x; Bs[lk4 + 1][lr] = b0.y; Bs[lk4 + 2][lr] = b0.z; Bs[lk4 + 3][lr] = b0.w;
    Bs[lk4 + 0][lr + 32] = b1.x; Bs[lk4 + 1][lr + 32] = b1.y; Bs[lk4 + 2][lr + 32] = b1.z; Bs[lk4 + 3][lr + 32] = b1.w;
    __syncthreads();
    #pragma unroll
    for (int kk = 0; kk < 32; ++kk) {
      float4 av = *(const float4*)&As[kk][ty << 2];
      float4 bv = *(const float4*)&Bs[kk][tx << 2];
      acc[0][0] = fmaf(av.x, bv.x, acc[0][0]); acc[0][1] = fmaf(av.x, bv.y, acc[0][1]);
      acc[0][2] = fmaf(av.x, bv.z, acc[0][2]); acc[0][3] = fmaf(av.x, bv.w, acc[0][3]);
      acc[1][0] = fmaf(av.y, bv.x, acc[1][0]); acc[1][1] = fmaf(av.y, bv.y, acc[1][1]);
      acc[1][2] = fmaf(av.y, bv.z, acc[1][2]); acc[1][3] = fmaf(av.y, bv.w, acc[1][3]);
      acc[2][0] = fmaf(av.z, bv.x, acc[2][0]); acc[2][1] = fmaf(av.z, bv.y, acc[2][1]);
      acc[2][2] = fmaf(av.z, bv.z, acc[2][2]); acc[2][3] = fmaf(av.z, bv.w, acc[2][3]);
      acc[3][0] = fmaf(av.w, bv.x, acc[3][0]); acc[3][1] = fmaf(av.w, bv.y, acc[3][1]);
      acc[3][2] = fmaf(av.w, bv.z, acc[3][2]); acc[3][3] = fmaf(av.w, bv.w, acc[3][3]);
    }
  }
  float* Pz = P + ((size_t)blockIdx.z << 18);       // slice stride 262144
  #pragma unroll
  for (int i = 0; i < 4; ++i) {
    int m = m0 + (ty << 2) + i;
    #pragma unroll
    for (int j = 0; j < 4; ++j)
      Pz[(size_t)m * 2048 + n0 + (tx << 2) + j] = acc[i][j];
  }
}

// ---------------------------------------------------------------------------
// K5: expert fused epilogue (column-oriented, block owns whole columns):
// reduce 8 partials + bias -> y (regs) -> stats(y) -> xl=relu(bn(y)) -> write
// -> stats(xl) -> write affine params for hl and hf-first-half.
// 128 blocks x (16 cols x 16 rowgroups of 8)
// ---------------------------------------------------------------------------
__global__ __launch_bounds__(256) void expert_fused_kernel(
    const float* __restrict__ Pe, const float* __restrict__ e_b,
    const float* __restrict__ e_g, const float* __restrict__ e_bb,
    const float* __restrict__ hl_g1, const float* __restrict__ hl_b1,
    const float* __restrict__ hf_g1, const float* __restrict__ hf_b1,
    float* __restrict__ xl,
    float* __restrict__ s_l, float* __restrict__ t_l,
    float* __restrict__ sf1, float* __restrict__ tf1) {
  const int ci = threadIdx.x & 15;
  const int g  = threadIdx.x >> 4;
  const int c  = blockIdx.x * 16 + ci;
  float v[8];
  float s = 0.f, q = 0.f;
  const float bias = e_b[c];
  #pragma unroll
  for (int r = 0; r < 8; ++r) {
    const size_t row = g * 8 + r;
    float acc = bias;
    #pragma unroll
    for (int z = 0; z < 8; ++z)
      acc += Pe[((size_t)z << 18) + row * 2048 + c];
    v[r] = acc; s += acc; q += acc * acc;
  }
  __shared__ float ss[16][16], qq[16][16];
  __shared__ float sm[16], sr[16];
  ss[g][ci] = s; qq[g][ci] = q;
  __syncthreads();
  if (g == 0) {
    float S = 0.f, Q = 0.f;
    #pragma unroll
    for (int j = 0; j < 16; ++j) { S += ss[j][ci]; Q += qq[j][ci]; }
    float m = S * (1.f / B_DIM);
    float var = Q * (1.f / B_DIM) - m * m;
    if (var < 0.f) var = 0.f;
    sm[ci] = m; sr[ci] = rsqrtf(var + 1e-5f);
  }
  __syncthreads();
  const float m = sm[ci], rst = sr[ci];
  const float eg = e_g[c], eb2 = e_bb[c];
  float s2 = 0.f, q2 = 0.f;
  #pragma unroll
  for (int r = 0; r < 8; ++r) {
    float xv = fmaxf((v[r] - m) * rst * eg + eb2, 0.f);
    xl[(size_t)(g * 8 + r) * 2048 + c] = xv;
    s2 += xv; q2 += xv * xv;
  }
  __syncthreads();
  ss[g][ci] = s2; qq[g][ci] = q2;
  __syncthreads();
  if (g == 0) {
    float S = 0.f, Q = 0.f;
    #pragma unroll
    for (int j = 0; j < 16; ++j) { S += ss[j][ci]; Q += qq[j][ci]; }
    float mm = S * (1.f / B_DIM);
    float var = Q * (1.f / B_DIM) - mm * mm;
    if (var < 0.f) var = 0.f;
    float rr = rsqrtf(var + 1e-5f);
    float a = rr * hl_g1[c]; s_l[c] = a; t_l[c] = hl_b1[c] - mm * a;
    float b = rr * hf_g1[c]; sf1[c] = b; tf1[c] = hf_b1[c] - mm * b;
  }
}

// ---------------------------------------------------------------------------
// K6: combined head-linear1 split-K GEMM with BN1 affine folded into A-load.
// jobs by blockIdx.x: [0,8)=hl (A=xl), [8,16)=hh (A=mp), [16,32)=hf (A=xl|mp).
// grid (32, 2, 16). Kc: l/h=128, f=256.
// ---------------------------------------------------------------------------
__global__ __launch_bounds__(256) void gemm_w1_kernel(
    const float* __restrict__ xl, const float* __restrict__ mp,
    const float* __restrict__ s_l, const float* __restrict__ t_l,
    const float* __restrict__ s_h, const float* __restrict__ t_h,
    const float* __restrict__ sf1, const float* __restrict__ tf1,
    const float* __restrict__ sf2, const float* __restrict__ tf2,
    const float* __restrict__ hl_w1, const float* __restrict__ hh_w1,
    const float* __restrict__ hf_w1,
    float* __restrict__ P_l, float* __restrict__ P_h, float* __restrict__ P_f) {
  const int jx = blockIdx.x;
  const int z  = blockIdx.z;
  const float *A, *S, *T, *Wt;
  float* P;
  int N, K, n0, kA, kW, Kc;
  if (jx < 8) {
    N = 512; K = 2048; Kc = 128; Wt = hl_w1; n0 = jx << 6;
    kW = z * 128; kA = kW; A = xl; S = s_l; T = t_l;
    P = P_l + ((size_t)z << 16);
  } else if (jx < 16) {
    N = 512; K = 2048; Kc = 128; Wt = hh_w1; n0 = (jx - 8) << 6;
    kW = z * 128; kA = kW; A = mp; S = s_h; T = t_h;
    P = P_h + ((size_t)z << 16);
  } else {
    N = 1024; K = 4096; Kc = 256; Wt = hf_w1; n0 = (jx - 16) << 6;
    kW = z * 256;
    if (kW >= 2048) { A = mp; S = sf2; T = tf2; kA = kW - 2048; }
    else            { A = xl; S = sf1; T = tf1; kA = kW; }
    P = P_f + ((size_t)z << 17);
  }
  const int m0 = blockIdx.y << 6;
  __shared__ float As[32][68];
  __shared__ float Bs[32][68];
  const int t = threadIdx.x;
  const int lr = t >> 3;
  const int lk4 = (t & 7) << 2;
  const int tx = t & 15, ty = t >> 4;
  float acc[4][4] = {{0.f}};
  for (int k0 = 0; k0 < Kc; k0 += 32) {
    const int ka = kA + k0 + lk4;
    float4 a0 = *(const float4*)&A[(size_t)(m0 + lr) * 2048 + ka];
    float4 a1 = *(const float4*)&A[(size_t)(m0 + lr + 32) * 2048 + ka];
    float4 s4 = *(const float4*)&S[ka];
    float4 t4 = *(const float4*)&T[ka];
    a0.x = fmaf(a0.x, s4.x, t4.x); a0.y = fmaf(a0.y, s4.y, t4.y);
    a0.z = fmaf(a0.z, s4.z, t4.z); a0.w = fmaf(a0.w, s4.w, t4.w);
    a1.x = fmaf(a1.x, s4.x, t4.x); a1.y = fmaf(a1.y, s4.y, t4.y);
    a1.z = fmaf(a1.z, s4.z, t4.z); a1.w = fmaf(a1.w, s4.w, t4.w);
    const int kw = kW + k0 + lk4;
    float4 b0 = *(const float4*)&Wt[(size_t)(n0 + lr) * K + kw];
    float4 b1 = *(const float4*)&Wt[(size_t)(n0 + lr + 32) * K + kw];
    __syncthreads();
    As[lk4 + 0][lr] = a0.x; As[lk4 + 1][lr] = a0.y; As[lk4 + 2][lr] = a0.z; As[lk4 + 3][lr] = a0.w;
    As[lk4 + 0][lr + 32] = a1.x; As[lk4 + 1][lr + 32] = a1.y; As[lk4 + 2][lr + 32] = a1.z; As[lk4 + 3][lr + 32] = a1.w;
    Bs[lk4 + 0][lr] = b0.x; Bs[lk4 + 1][lr] = b0.y; Bs[lk4 + 2][lr] = b0.z; Bs[lk4 + 3][lr] = b0.w;
    Bs[lk4 + 0][lr + 32] = b1.x; Bs[lk4 + 1][lr + 32] = b1.y; Bs[lk4 + 2][lr + 32] = b1.z; Bs[lk4 + 3][lr + 32] = b1.w;
    __syncthreads();
    #pragma unroll
    for (int kk = 0; kk < 32; ++kk) {
      float4 av = *(const float4*)&As[kk][ty << 2];
      float4 bv = *(const float4*)&Bs[kk][tx << 2];
      acc[0][0] = fmaf(av.x, bv.x, acc[0][0]); acc[0][1] = fmaf(av.x, bv.y, acc[0][1]);
      acc[0][2] = fmaf(av.x, bv.z, acc[0][2]); acc[0][3] = fmaf(av.x, bv.w, acc[0][3]);
      acc[1][0] = fmaf(av.y, bv.x, acc[1][0]); acc[1][1] = fmaf(av.y, bv.y, acc[1][1]);
      acc[1][2] = fmaf(av.y, bv.z, acc[1][2]); acc[1][3] = fmaf(av.y, bv.w, acc[1][3]);
      acc[2][0] = fmaf(av.z, bv.x, acc[2][0]); acc[2][1] = fmaf(av.z, bv.y, acc[2][1]);
      acc[2][2] = fmaf(av.z, bv.z, acc[2][2]); acc[2][3] = fmaf(av.z, bv.w, acc[2][3]);
      acc[3][0] = fmaf(av.w, bv.x, acc[3][0]); acc[3][1] = fmaf(av.w, bv.y, acc[3][1]);
      acc[3][2] = fmaf(av.w, bv.z, acc[3][2]); acc[3][3] = fmaf(av.w, bv.w, acc[3][3]);
    }
  }
  #pragma unroll
  for (int i = 0; i < 4; ++i) {
    int m = m0 + (ty << 2) + i;
    #pragma unroll
    for (int j = 0; j < 4; ++j)
      P[(size_t)m * N + n0 + (tx << 2) + j] = acc[i][j];
  }
}

// ---------------------------------------------------------------------------
// K7: heads fused epilogue: reduce 16 partial slices + bias -> h1 (regs) ->
// stats -> a2 = elu(bn(h1)) -> write. 128 blocks x (16 cols x 16 rowgroups).
// column space: [0,512)=l, [512,1024)=h, [1024,2048)=f
// ---------------------------------------------------------------------------
__global__ __launch_bounds__(256) void heads_fused_kernel(
    const float* __restrict__ P_l, const float* __restrict__ P_h,
    const float* __restrict__ P_f,
    const float* __restrict__ bl1, const float* __restrict__ bh1,
    const float* __restrict__ bf1,
    const float* __restrict__ g2l, const float* __restrict__ b2l,
    const float* __restrict__ g2h, const float* __restrict__ b2h,
    const float* __restrict__ g2f, const float* __restrict__ b2f,
    float* __restrict__ a2_l, float* __restrict__ a2_h, float* __restrict__ a2_f) {
  const int ci = threadIdx.x & 15;
  const int g  = threadIdx.x >> 4;
  const int cj = blockIdx.x * 16 + ci;
  const float *P, *bi, *g2, *b2;
  float* out;
  int N, cc;
  if (cj < 512)       { P = P_l; bi = bl1; g2 = g2l; b2 = b2l; out = a2_l; N = 512;  cc = cj; }
  else if (cj < 1024) { P = P_h; bi = bh1; g2 = g2h; b2 = b2h; out = a2_h; N = 512;  cc = cj - 512; }
  else                { P = P_f; bi = bf1; g2 = g2f; b2 = b2f; out = a2_f; N = 1024; cc = cj - 1024; }
  const size_t sstride = (size_t)N * 128;
  float v[8];
  float s = 0.f, q = 0.f;
  const float bias = bi[cc];
  #pragma unroll
  for (int r = 0; r < 8; ++r) {
    const size_t row = g * 8 + r;
    float acc = bias;
    #pragma unroll
    for (int z = 0; z < 16; ++z)
      acc += P[(size_t)z * sstride + row * N + cc];
    v[r] = acc; s += acc; q += acc * acc;
  }
  __shared__ float ss[16][16], qq[16][16];
  __shared__ float sm[16], sr[16];
  ss[g][ci] = s; qq[g][ci] = q;
  __syncthreads();
  if (g == 0) {
    float S = 0.f, Q = 0.f;
    #pragma unroll
    for (int j = 0; j < 16; ++j) { S += ss[j][ci]; Q += qq[j][ci]; }
    float m = S * (1.f / B_DIM);
    float var = Q * (1.f / B_DIM) - m * m;
    if (var < 0.f) var = 0.f;
    sm[ci] = m; sr[ci] = rsqrtf(var + 1e-5f);
  }
  __syncthreads();
  const float m = sm[ci], rr = sr[ci];
  const float gg = g2[cc], bb = b2[cc];
  #pragma unroll
  for (int r = 0; r < 8; ++r) {
    float xn = (v[r] - m) * rr * gg + bb;
    out[(size_t)(g * 8 + r) * N + cc] = xn > 0.f ? xn : expm1f(xn);
  }
}

// ---------------------------------------------------------------------------
// K8: combined head-linear2 split-K GEMM. jobs: [0,4)=l, [4,8)=h, [8,12)=f
// grid (12, 2, 8). Kc: l/h=64, f=128. Partials in [z][76800] layout.
// ---------------------------------------------------------------------------
__global__ __launch_bounds__(256) void gemm_w2_kernel(
    const float* __restrict__ a2_l, const float* __restrict__ a2_h,
    const float* __restrict__ a2_f,
    const float* __restrict__ hl_w2, const float* __restrict__ hh_w2,
    const float* __restrict__ hf_w2,
    float* __restrict__ Pw) {
  const int jx = blockIdx.x;
  const int z  = blockIdx.z;
  const float *A, *Wt;
  int K, Kc, pOff, n0;
  if (jx < 4)      { A = a2_l; Wt = hl_w2; K = 512;  Kc = 64;  pOff = 0;     n0 = jx << 6; }
  else if (jx < 8) { A = a2_h; Wt = hh_w2; K = 512;  Kc = 64;  pOff = 25600; n0 = (jx - 4) << 6; }
  else             { A = a2_f; Wt = hf_w2; K = 1024; Kc = 128; pOff = 51200; n0 = (jx - 8) << 6; }
  const int kbeg = z * Kc;
  const int m0 = blockIdx.y << 6;
  __shared__ float As[32][68];
  __shared__ float Bs[32][68];
  const int t = threadIdx.x;
  const int lr = t >> 3;
  const int lk4 = (t & 7) << 2;
  const int tx = t & 15, ty = t >> 4;
  float acc[4][4] = {{0.f}};
  const float4 z4 = make_float4(0.f, 0.f, 0.f, 0.f);
  for (int k0 = kbeg; k0 < kbeg + Kc; k0 += 32) {
    float4 a0 = *(const float4*)&A[(size_t)(m0 + lr) * K + k0 + lk4];
    float4 a1 = *(const float4*)&A[(size_t)(m0 + lr + 32) * K + k0 + lk4];
    int n1 = n0 + lr, n2 = n0 + lr + 32;
    float4 b0 = (n1 < 200) ? *(const float4*)&Wt[(size_t)n1 * K + k0 + lk4] : z4;
    float4 b1 = (n2 < 200) ? *(const float4*)&Wt[(size_t)n2 * K + k0 + lk4] : z4;
    __syncthreads();
    As[lk4 + 0][lr] = a0.x; As[lk4 + 1][lr] = a0.y; As[lk4 + 2][lr] = a0.z; As[lk4 + 3][lr] = a0.w;
    As[lk4 + 0][lr + 32] = a1.x; As[lk4 + 1][lr + 32] = a1.y; As[lk4 + 2][lr + 32] = a1.z; As[lk4 + 3][lr + 32] = a1.w;
    Bs[lk4 + 0][lr] = b0.x; Bs[lk4 + 1][lr] = b0.y; Bs[lk4 + 2][lr] = b0.z; Bs[lk4 + 3][lr] = b0.w;
    Bs[lk4 + 0][lr + 32] = b1.x; Bs[lk4 + 1][lr + 32] = b1.y; Bs[lk4 + 2][lr + 32] = b1.z; Bs[lk4 + 3][lr + 32] = b1.w;
    __syncthreads();
    #pragma unroll
    for (int kk = 0; kk < 32; ++kk) {
      float4 av = *(const float4*)&As[kk][ty << 2];
      float4 bv = *(const float4*)&Bs[kk][tx << 2];
      acc[0][0] = fmaf(av.x, bv.x, acc[0][0]); acc[0][1] = fmaf(av.x, bv.y, acc[0][1]);
      acc[0][2] = fmaf(av.x, bv.z, acc[0][2]); acc[0][3] = fmaf(av.x, bv.w, acc[0][3]);
      acc[1][0] = fmaf(av.y, bv.x, acc[1][0]); acc[1][1] = fmaf(av.y, bv.y, acc[1][1]);
      acc[1][2] = fmaf(av.y, bv.z, acc[1][2]); acc[1][3] = fmaf(av.y, bv.w, acc[1][3]);
      acc[2][0] = fmaf(av.z, bv.x, acc[2][0]); acc[2][1] = fmaf(av.z, bv.y, acc[2][1]);
      acc[2][2] = fmaf(av.z, bv.z, acc[2][2]); acc[2][3] = fmaf(av.z, bv.w, acc[2][3]);
      acc[3][0] = fmaf(av.w, bv.x, acc[3][0]); acc[3][1] = fmaf(av.w, bv.y, acc[3][1]);
      acc[3][2] = fmaf(av.w, bv.z, acc[3][2]); acc[3][3] = fmaf(av.w, bv.w, acc[3][3]);
    }
  }
  float* Pz = Pw + (size_t)z * 76800 + pOff;
  #pragma unroll
  for (int i = 0; i < 4; ++i) {
    int m = m0 + (ty << 2) + i;
    #pragma unroll
    for (int j = 0; j < 4; ++j) {
      int n = n0 + (tx << 2) + j;
      if (n < 200) Pz[(size_t)m * 200 + n] = acc[i][j];
    }
  }
}

// K9: final reduce into out (3 outputs concatenated)
__global__ void reduce_out_kernel(const float* __restrict__ P,
                                  const float* __restrict__ bl,
                                  const float* __restrict__ bh,
                                  const float* __restrict__ bf,
                                  float* __restrict__ out) {
  int i = blockIdx.x * 256 + threadIdx.x;
  if (i >= 76800) return;
  int job = i / 25600;
  int n = (i - job * 25600) % 200;
  float s = (job == 0) ? bl[n] : (job == 1) ? bh[n] : bf[n];
  for (int z = 0; z < 8; ++z) s += P[(size_t)z * 76800 + i];
  out[i] = s;
}

// ---------------------------------------------------------------------------
extern "C" void kernel_launch(void* const* d_in, const int* in_sizes, int n_in,
                              void* d_out, int out_size, void* d_ws, size_t ws_size,
                              hipStream_t stream) {
  const float* x      = (const float*)d_in[0];
  const float* g_bn_g = (const float*)d_in[1];
  const float* g_bn_b = (const float*)d_in[2];
  const float* g_w    = (const float*)d_in[3];
  const float* g_b    = (const float*)d_in[4];
  const float* e_w    = (const float*)d_in[5];
  const float* e_b    = (const float*)d_in[6];
  const float* e_g    = (const float*)d_in[7];
  const float* e_bb   = (const float*)d_in[8];
  const float* hl_g1  = (const float*)d_in[9];
  const float* hl_b1  = (const float*)d_in[10];
  const float* hl_w1  = (const float*)d_in[11];
  const float* hl_bi1 = (const float*)d_in[12];
  const float* hl_g2  = (const float*)d_in[13];
  const float* hl_b2  = (const float*)d_in[14];
  const float* hl_w2  = (const float*)d_in[15];
  const float* hl_bi2 = (const float*)d_in[16];
  const float* hh_g1  = (const float*)d_in[17];
  const float* hh_b1  = (const float*)d_in[18];
  const float* hh_w1  = (const float*)d_in[19];
  const float* hh_bi1 = (const float*)d_in[20];
  const float* hh_g2  = (const float*)d_in[21];
  const float* hh_b2  = (const float*)d_in[22];
  const float* hh_w2  = (const float*)d_in[23];
  const float* hh_bi2 = (const float*)d_in[24];
  const float* hf_g1  = (const float*)d_in[25];
  const float* hf_b1  = (const float*)d_in[26];
  const float* hf_w1  = (const float*)d_in[27];
  const float* hf_bi1 = (const float*)d_in[28];
  const float* hf_g2  = (const float*)d_in[29];
  const float* hf_b2  = (const float*)d_in[30];
  const float* hf_w2  = (const float*)d_in[31];
  const float* hf_bi2 = (const float*)d_in[32];
  float* out = (float*)d_out;

  float* W = (float*)d_ws;
  const size_t BC = (size_t)B_DIM * C_DIM;   // 262144
  float* mp   = W;                           // [128,2048]
  float* ms   = mp + BC;                     // [128,2048,4]
  float* pool = ms + BC * 4;                 // [128,2048]
  float* xl   = pool + BC;                   // [128,2048]
  float* a2_l = xl + BC;                     // [128,512]
  float* a2_h = a2_l + 128 * 512;
  float* a2_f = a2_h + 128 * 512;            // [128,1024]
  float* st   = a2_f + 128 * 1024;
  float* mean_mp = st;           float* rstd_mp = st + 2048;
  float* s_h  = st + 2 * 2048;   float* t_h  = st + 3 * 2048;
  float* sf2  = st + 4 * 2048;   float* tf2  = st + 5 * 2048;
  float* s_l  = st + 6 * 2048;   float* t_l  = st + 7 * 2048;
  float* sf1  = st + 8 * 2048;   float* tf1  = st + 9 * 2048;
  float* P_e  = st + 10 * 2048;                 // 8 x 262144 (reused as P_w2)
  float* P_l2 = P_e + 8 * BC;                   // 16 x 65536
  float* P_hh = P_l2 + (size_t)16 * 65536;      // 16 x 65536
  float* P_f  = P_hh + (size_t)16 * 65536;      // 16 x 131072
  float* P_w2 = P_e;

  pool_max_kernel<<<16384, 256, 0, stream>>>(x, mp, ms);

  statsmp_kernel<<<128, 256, 0, stream>>>(mp, hh_g1, hh_b1, hf_g1, hf_b1,
                                          mean_mp, rstd_mp, s_h, t_h, sf2, tf2);

  gate_select_kernel<<<128, 256, 0, stream>>>(mp, mean_mp, rstd_mp, g_bn_g, g_bn_b,
                                              g_w, g_b, ms, pool);

  gemm_e_kernel<<<dim3(32, 2, 8), 256, 0, stream>>>(pool, e_w, P_e);

  expert_fused_kernel<<<128, 256, 0, stream>>>(P_e, e_b, e_g, e_bb,
                                               hl_g1, hl_b1, hf_g1, hf_b1,
                                               xl, s_l, t_l, sf1, tf1);

  gemm_w1_kernel<<<dim3(32, 2, 16), 256, 0, stream>>>(
      xl, mp, s_l, t_l, s_h, t_h, sf1, tf1, sf2, tf2,
      hl_w1, hh_w1, hf_w1, P_l2, P_hh, P_f);

  heads_fused_kernel<<<128, 256, 0, stream>>>(
      P_l2, P_hh, P_f, hl_bi1, hh_bi1, hf_bi1,
      hl_g2, hl_b2, hh_g2, hh_b2, hf_g2, hf_b2,
      a2_l, a2_h, a2_f);

  gemm_w2_kernel<<<dim3(12, 2, 8), 256, 0, stream>>>(
      a2_l, a2_h, a2_f, hl_w2, hh_w2, hf_w2, P_w2);

  reduce_out_kernel<<<300, 256, 0, stream>>>(P_w2, hl_bi2, hh_bi2, hf_bi2, out);
}

// Round 7
// 139.497 us; speedup vs baseline: 9.1731x; 1.1366x over previous
//
#include <hip/hip_runtime.h>
#include <math.h>

#define B_DIM 128
#define C_DIM 2048
#define HW2   196

typedef __attribute__((ext_vector_type(8))) short bf16x8;
typedef __attribute__((ext_vector_type(4))) float f32x4;

__device__ __forceinline__ unsigned short f2bf(float f) {
  unsigned u = __float_as_uint(f);
  u += 0x7FFFu + ((u >> 16) & 1u);     // RNE
  return (unsigned short)(u >> 16);
}

// ---------------------------------------------------------------------------
// K1: per-(b,c) 14x14 tile -> global max (mp) + 4-scale adaptive avg-pool max.
// Register-resident separable pooling (see R4 notes).
// ---------------------------------------------------------------------------
__global__ __launch_bounds__(256) void pool_max_kernel(
    const float* __restrict__ x, float* __restrict__ mp, float* __restrict__ ms) {
  __shared__ float lds[4][4][208];
  const int tid  = threadIdx.x;
  const int w    = tid >> 6;
  const int lane = tid & 63;
  const int g    = lane >> 4;
  const int c    = lane & 15;
  const size_t waveBase = (size_t)blockIdx.x * 16 + w * 4;

  const float* src = x + waveBase * HW2;
  #pragma unroll
  for (int j = 0; j < 4; ++j) {
    int f = lane + 64 * j;
    if (f < 196) {
      int t = (f * 669) >> 15;       // f / 49
      float4 v = *(const float4*)(src + f * 4);
      *(float4*)&lds[w][t][(f - 49 * t) * 4] = v;
    }
  }

  float xv[14];
  const float* col = &lds[w][g][c];
  #pragma unroll
  for (int r = 0; r < 14; ++r) xv[r] = col[r * 14];

  float cmax = (c < 14) ? xv[0] : -INFINITY;
  #pragma unroll
  for (int r = 1; r < 14; ++r) if (c < 14) cmax = fmaxf(cmax, xv[r]);
  #pragma unroll
  for (int off = 8; off > 0; off >>= 1) cmax = fmaxf(cmax, __shfl_xor(cmax, off));

  float P[15];
  P[0] = 0.f;
  #pragma unroll
  for (int r = 0; r < 14; ++r) P[r + 1] = P[r] + xv[r];

  float sm0, sm1, sm2, sm3;

  { // k=4
    constexpr int rs[4] = {0, 3, 7, 10}, re[4] = {4, 7, 11, 14};
    const bool valid = (0x489u >> c) & 1;
    float vmax = -INFINITY;
    #pragma unroll
    for (int i = 0; i < 4; ++i) {
      float v  = P[re[i]] - P[rs[i]];
      float w2 = v + __shfl_down(v, 1);
      float w4 = w2 + __shfl_down(w2, 2);
      vmax = fmaxf(vmax, valid ? w4 : -INFINITY);
    }
    #pragma unroll
    for (int off = 8; off > 0; off >>= 1) vmax = fmaxf(vmax, __shfl_xor(vmax, off));
    sm0 = vmax * 0.0625f;
  }
  { // k=5
    constexpr int rs[5] = {0, 2, 5, 8, 11}, re[5] = {3, 6, 9, 12, 14};
    constexpr float srl[5] = {1.f/3.f, 0.25f, 0.25f, 0.25f, 1.f/3.f};
    const bool valid = (0x925u >> c) & 1;
    const bool is3   = (0x801u >> c) & 1;
    const float invc = is3 ? (1.f/3.f) : 0.25f;
    float vmax = -INFINITY;
    #pragma unroll
    for (int i = 0; i < 5; ++i) {
      float v  = P[re[i]] - P[rs[i]];
      float d1 = __shfl_down(v, 1);
      float d2 = __shfl_down(v, 2);
      float w2 = v + d1;
      float w3 = w2 + d2;
      float w4 = w2 + __shfl_down(w2, 2);
      float wv = (is3 ? w3 : w4) * invc * srl[i];
      vmax = fmaxf(vmax, valid ? wv : -INFINITY);
    }
    #pragma unroll
    for (int off = 8; off > 0; off >>= 1) vmax = fmaxf(vmax, __shfl_xor(vmax, off));
    sm1 = vmax;
  }
  { // k=7
    constexpr int rs[7] = {0, 2, 4, 6, 8, 10, 12};
    const bool valid = (0x1555u >> c) & 1;
    float vmax = -INFINITY;
    #pragma unroll
    for (int i = 0; i < 7; ++i) {
      float v  = P[rs[i] + 2] - P[rs[i]];
      float w2 = v + __shfl_down(v, 1);
      vmax = fmaxf(vmax, valid ? w2 : -INFINITY);
    }
    #pragma unroll
    for (int off = 8; off > 0; off >>= 1) vmax = fmaxf(vmax, __shfl_xor(vmax, off));
    sm2 = vmax * 0.25f;
  }
  { // k=11
    constexpr int rs[11] = {0, 1, 2, 3, 5, 6, 7, 8, 10, 11, 12};
    constexpr int re[11] = {2, 3, 4, 6, 7, 8, 9, 11, 12, 13, 14};
    constexpr float srl[11] = {0.5f, 0.5f, 0.5f, 1.f/3.f, 0.5f, 0.5f, 0.5f,
                               1.f/3.f, 0.5f, 0.5f, 0.5f};
    const bool valid = (0x1DEFu >> c) & 1;
    const bool is3   = (0x108u >> c) & 1;
    const float invc = is3 ? (1.f/3.f) : 0.5f;
    float vmax = -INFINITY;
    #pragma unroll
    for (int i = 0; i < 11; ++i) {
      float v  = P[re[i]] - P[rs[i]];
      float d1 = __shfl_down(v, 1);
      float d2 = __shfl_down(v, 2);
      float w2 = v + d1;
      float w3 = w2 + d2;
      float wv = (is3 ? w3 : w2) * invc * srl[i];
      vmax = fmaxf(vmax, valid ? wv : -INFINITY);
    }
    #pragma unroll
    for (int off = 8; off > 0; off >>= 1) vmax = fmaxf(vmax, __shfl_xor(vmax, off));
    sm3 = vmax;
  }

  if (c == 0) {
    size_t T = waveBase + g;
    mp[T] = cmax;
    *(float4*)&ms[T * 4] = make_float4(sm0, sm1, sm2, sm3);
  }
}

// ---------------------------------------------------------------------------
// K2: mp column stats + affine params (hh head, hf second half)
// ---------------------------------------------------------------------------
__global__ __launch_bounds__(256) void statsmp_kernel(
    const float* __restrict__ mp,
    const float* __restrict__ hh_g1, const float* __restrict__ hh_b1,
    const float* __restrict__ hf_g1, const float* __restrict__ hf_b1,
    float* __restrict__ mean_mp, float* __restrict__ rstd_mp,
    float* __restrict__ s_h, float* __restrict__ t_h,
    float* __restrict__ sf2, float* __restrict__ tf2) {
  const int ci = threadIdx.x & 15;
  const int g  = threadIdx.x >> 4;
  const int c  = blockIdx.x * 16 + ci;
  float s = 0.f, q = 0.f;
  #pragma unroll
  for (int r = 0; r < 8; ++r) {
    float v = mp[(size_t)(g * 8 + r) * C_DIM + c];
    s += v; q += v * v;
  }
  __shared__ float ss[16][16], qq[16][16];
  ss[g][ci] = s; qq[g][ci] = q;
  __syncthreads();
  if (g == 0) {
    float S = 0.f, Q = 0.f;
    #pragma unroll
    for (int j = 0; j < 16; ++j) { S += ss[j][ci]; Q += qq[j][ci]; }
    float m = S * (1.f / B_DIM);
    float var = Q * (1.f / B_DIM) - m * m;
    if (var < 0.f) var = 0.f;
    float r = rsqrtf(var + 1e-5f);
    mean_mp[c] = m; rstd_mp[c] = r;
    float a = r * hh_g1[c];        s_h[c] = a; t_h[c] = hh_b1[c] - m * a;
    float b = r * hf_g1[2048 + c]; sf2[c] = b; tf2[c] = hf_b1[2048 + c] - m * b;
  }
}

// ---------------------------------------------------------------------------
// K3: gate (BN+ELU+linear+argmax) fused with gated scale select -> pool
// ---------------------------------------------------------------------------
__global__ void gate_select_kernel(
    const float* __restrict__ mp,
    const float* __restrict__ mean, const float* __restrict__ rstd,
    const float* __restrict__ gg, const float* __restrict__ gb,
    const float* __restrict__ gw, const float* __restrict__ gbias,
    const float* __restrict__ ms, float* __restrict__ pool) {
  const int b = blockIdx.x;
  const int t = threadIdx.x;
  float s0 = 0.f, s1 = 0.f, s2 = 0.f, s3 = 0.f;
  for (int c = t; c < C_DIM; c += 256) {
    float v = mp[(size_t)b * C_DIM + c];
    float xn = (v - mean[c]) * rstd[c] * gg[c] + gb[c];
    float e = xn > 0.f ? xn : expm1f(xn);
    s0 += e * gw[c];
    s1 += e * gw[C_DIM + c];
    s2 += e * gw[2 * C_DIM + c];
    s3 += e * gw[3 * C_DIM + c];
  }
  __shared__ float red[4][256];
  __shared__ int ssel;
  red[0][t] = s0; red[1][t] = s1; red[2][t] = s2; red[3][t] = s3;
  __syncthreads();
  for (int st = 128; st > 0; st >>= 1) {
    if (t < st) {
      red[0][t] += red[0][t + st];
      red[1][t] += red[1][t + st];
      red[2][t] += red[2][t + st];
      red[3][t] += red[3][t + st];
    }
    __syncthreads();
  }
  if (t == 0) {
    float best = red[0][0] + gbias[0];
    int bi = 0;
    for (int j = 1; j < 4; ++j) {
      float l = red[j][0] + gbias[j];
      if (l > best) { best = l; bi = j; }
    }
    ssel = bi;
  }
  __syncthreads();
  const int sel = ssel;
  for (int c = t; c < C_DIM; c += 256)
    pool[(size_t)b * C_DIM + c] = ms[((size_t)b * C_DIM + c) * 4 + sel];
}

// ---------------------------------------------------------------------------
// K4: expert GEMM, bf16 MFMA. C[128,2048] partials = pool @ e_w^T.
// BM=128 BN=64 BK=64. grid (N/64=32, z=8), Kc=256. fp32->bf16 in staging.
// LDS XOR-swizzle: 16B-slot ^= (row&7) on write and read (G4).
// ---------------------------------------------------------------------------
__global__ __launch_bounds__(256) void gemm_e_mfma_kernel(
    const float* __restrict__ A, const float* __restrict__ W,
    float* __restrict__ P) {
  __shared__ __align__(16) short As[128 * 64];
  __shared__ __align__(16) short Bs[64 * 64];
  const int t = threadIdx.x;
  const int n0 = blockIdx.x << 6;
  const int kbeg = blockIdx.y << 8;          // Kc = 256

  const int rowA = t >> 1, koffA = (t & 1) << 5;   // 128 rows x 32 k
  const int rowB = t >> 2, koffB = (t & 3) << 4;   // 64 rows x 16 k

  const int lane = t & 63, wav = t >> 6;
  const int r = lane & 15, kb = lane >> 4;
  int aoff[2][2], boff[2][4];
  #pragma unroll
  for (int kk = 0; kk < 2; ++kk) {
    #pragma unroll
    for (int mi = 0; mi < 2; ++mi) {
      int row = wav * 32 + mi * 16 + r;
      aoff[kk][mi] = row * 128 + ((((kk << 2) + kb) ^ (row & 7)) << 4);
    }
    #pragma unroll
    for (int ni = 0; ni < 4; ++ni) {
      int cl = ni * 16 + r;
      boff[kk][ni] = cl * 128 + ((((kk << 2) + kb) ^ (cl & 7)) << 4);
    }
  }

  f32x4 acc[2][4];
  #pragma unroll
  for (int mi = 0; mi < 2; ++mi)
    #pragma unroll
    for (int ni = 0; ni < 4; ++ni)
      acc[mi][ni] = (f32x4){0.f, 0.f, 0.f, 0.f};

  for (int kt = 0; kt < 256; kt += 64) {
    const int kg = kbeg + kt;
    const float4* ap = (const float4*)&A[(size_t)rowA * 2048 + kg + koffA];
    const float4* bp = (const float4*)&W[(size_t)(n0 + rowB) * 2048 + kg + koffB];  // FIX: +n0
    float4 fa[8], fb[4];
    #pragma unroll
    for (int j = 0; j < 8; ++j) fa[j] = ap[j];
    #pragma unroll
    for (int j = 0; j < 4; ++j) fb[j] = bp[j];
    __syncthreads();
    #pragma unroll
    for (int j = 0; j < 4; ++j) {
      bf16x8 v;
      v[0] = (short)f2bf(fa[2*j].x);   v[1] = (short)f2bf(fa[2*j].y);
      v[2] = (short)f2bf(fa[2*j].z);   v[3] = (short)f2bf(fa[2*j].w);
      v[4] = (short)f2bf(fa[2*j+1].x); v[5] = (short)f2bf(fa[2*j+1].y);
      v[6] = (short)f2bf(fa[2*j+1].z); v[7] = (short)f2bf(fa[2*j+1].w);
      int slot = (koffA >> 3) + j;
      *(bf16x8*)((char*)As + rowA * 128 + ((slot ^ (rowA & 7)) << 4)) = v;
    }
    #pragma unroll
    for (int j = 0; j < 2; ++j) {
      bf16x8 v;
      v[0] = (short)f2bf(fb[2*j].x);   v[1] = (short)f2bf(fb[2*j].y);
      v[2] = (short)f2bf(fb[2*j].z);   v[3] = (short)f2bf(fb[2*j].w);
      v[4] = (short)f2bf(fb[2*j+1].x); v[5] = (short)f2bf(fb[2*j+1].y);
      v[6] = (short)f2bf(fb[2*j+1].z); v[7] = (short)f2bf(fb[2*j+1].w);
      int slot = (koffB >> 3) + j;
      *(bf16x8*)((char*)Bs + rowB * 128 + ((slot ^ (rowB & 7)) << 4)) = v;
    }
    __syncthreads();
    #pragma unroll
    for (int kk = 0; kk < 2; ++kk) {
      bf16x8 a0 = *(bf16x8*)((char*)As + aoff[kk][0]);
      bf16x8 a1 = *(bf16x8*)((char*)As + aoff[kk][1]);
      bf16x8 b0 = *(bf16x8*)((char*)Bs + boff[kk][0]);
      bf16x8 b1 = *(bf16x8*)((char*)Bs + boff[kk][1]);
      bf16x8 b2 = *(bf16x8*)((char*)Bs + boff[kk][2]);
      bf16x8 b3 = *(bf16x8*)((char*)Bs + boff[kk][3]);
      acc[0][0] = __builtin_amdgcn_mfma_f32_16x16x32_bf16(a0, b0, acc[0][0], 0, 0, 0);
      acc[0][1] = __builtin_amdgcn_mfma_f32_16x16x32_bf16(a0, b1, acc[0][1], 0, 0, 0);
      acc[0][2] = __builtin_amdgcn_mfma_f32_16x16x32_bf16(a0, b2, acc[0][2], 0, 0, 0);
      acc[0][3] = __builtin_amdgcn_mfma_f32_16x16x32_bf16(a0, b3, acc[0][3], 0, 0, 0);
      acc[1][0] = __builtin_amdgcn_mfma_f32_16x16x32_bf16(a1, b0, acc[1][0], 0, 0, 0);
      acc[1][1] = __builtin_amdgcn_mfma_f32_16x16x32_bf16(a1, b1, acc[1][1], 0, 0, 0);
      acc[1][2] = __builtin_amdgcn_mfma_f32_16x16x32_bf16(a1, b2, acc[1][2], 0, 0, 0);
      acc[1][3] = __builtin_amdgcn_mfma_f32_16x16x32_bf16(a1, b3, acc[1][3], 0, 0, 0);
    }
  }

  float* Pz = P + ((size_t)blockIdx.y << 18);
  #pragma unroll
  for (int mi = 0; mi < 2; ++mi) {
    int row = wav * 32 + mi * 16 + kb * 4;
    #pragma unroll
    for (int ni = 0; ni < 4; ++ni) {
      int cl = n0 + ni * 16 + r;
      #pragma unroll
      for (int g2 = 0; g2 < 4; ++g2)
        Pz[(size_t)(row + g2) * 2048 + cl] = acc[mi][ni][g2];
    }
  }
}

// ---------------------------------------------------------------------------
// K5: expert fused epilogue (reduce 8 partials + bias -> BN -> relu -> stats)
// ---------------------------------------------------------------------------
__global__ __launch_bounds__(256) void expert_fused_kernel(
    const float* __restrict__ Pe, const float* __restrict__ e_b,
    const float* __restrict__ e_g, const float* __restrict__ e_bb,
    const float* __restrict__ hl_g1, const float* __restrict__ hl_b1,
    const float* __restrict__ hf_g1, const float* __restrict__ hf_b1,
    float* __restrict__ xl,
    float* __restrict__ s_l, float* __restrict__ t_l,
    float* __restrict__ sf1, float* __restrict__ tf1) {
  const int ci = threadIdx.x & 15;
  const int g  = threadIdx.x >> 4;
  const int c  = blockIdx.x * 16 + ci;
  float v[8];
  float s = 0.f, q = 0.f;
  const float bias = e_b[c];
  #pragma unroll
  for (int r = 0; r < 8; ++r) {
    const size_t row = g * 8 + r;
    float acc = bias;
    #pragma unroll
    for (int z = 0; z < 8; ++z)
      acc += Pe[((size_t)z << 18) + row * 2048 + c];
    v[r] = acc; s += acc; q += acc * acc;
  }
  __shared__ float ss[16][16], qq[16][16];
  __shared__ float sm[16], sr[16];
  ss[g][ci] = s; qq[g][ci] = q;
  __syncthreads();
  if (g == 0) {
    float S = 0.f, Q = 0.f;
    #pragma unroll
    for (int j = 0; j < 16; ++j) { S += ss[j][ci]; Q += qq[j][ci]; }
    float m = S * (1.f / B_DIM);
    float var = Q * (1.f / B_DIM) - m * m;
    if (var < 0.f) var = 0.f;
    sm[ci] = m; sr[ci] = rsqrtf(var + 1e-5f);
  }
  __syncthreads();
  const float m = sm[ci], rst = sr[ci];
  const float eg = e_g[c], eb2 = e_bb[c];
  float s2 = 0.f, q2 = 0.f;
  #pragma unroll
  for (int r = 0; r < 8; ++r) {
    float xv = fmaxf((v[r] - m) * rst * eg + eb2, 0.f);
    xl[(size_t)(g * 8 + r) * 2048 + c] = xv;
    s2 += xv; q2 += xv * xv;
  }
  __syncthreads();
  ss[g][ci] = s2; qq[g][ci] = q2;
  __syncthreads();
  if (g == 0) {
    float S = 0.f, Q = 0.f;
    #pragma unroll
    for (int j = 0; j < 16; ++j) { S += ss[j][ci]; Q += qq[j][ci]; }
    float mm = S * (1.f / B_DIM);
    float var = Q * (1.f / B_DIM) - mm * mm;
    if (var < 0.f) var = 0.f;
    float rr = rsqrtf(var + 1e-5f);
    float a = rr * hl_g1[c]; s_l[c] = a; t_l[c] = hl_b1[c] - mm * a;
    float b = rr * hf_g1[c]; sf1[c] = b; tf1[c] = hf_b1[c] - mm * b;
  }
}

// ---------------------------------------------------------------------------
// K6: combined head-linear1 GEMM, bf16 MFMA, BN1 affine folded into A staging.
// grid (32, 16): bx=job/n-block, by=z. jobs: [0,8)=hl, [8,16)=hh, [16,32)=hf.
// ---------------------------------------------------------------------------
__global__ __launch_bounds__(256) void gemm_w1_mfma_kernel(
    const float* __restrict__ xl, const float* __restrict__ mp,
    const float* __restrict__ s_l, const float* __restrict__ t_l,
    const float* __restrict__ s_h, const float* __restrict__ t_h,
    const float* __restrict__ sf1, const float* __restrict__ tf1,
    const float* __restrict__ sf2, const float* __restrict__ tf2,
    const float* __restrict__ hl_w1, const float* __restrict__ hh_w1,
    const float* __restrict__ hf_w1,
    float* __restrict__ P_l, float* __restrict__ P_h, float* __restrict__ P_f) {
  __shared__ __align__(16) short As[128 * 64];
  __shared__ __align__(16) short Bs[64 * 64];
  const int jx = blockIdx.x;
  const int z  = blockIdx.y;
  const float *A, *S, *T, *Wt;
  float* P;
  int N, Kdim, n0, kA0, kW0, Kc;
  if (jx < 8) {
    N = 512; Kdim = 2048; Kc = 128; Wt = hl_w1; n0 = jx << 6;
    kW0 = z * 128; kA0 = kW0; A = xl; S = s_l; T = t_l;
    P = P_l + ((size_t)z << 16);
  } else if (jx < 16) {
    N = 512; Kdim = 2048; Kc = 128; Wt = hh_w1; n0 = (jx - 8) << 6;
    kW0 = z * 128; kA0 = kW0; A = mp; S = s_h; T = t_h;
    P = P_h + ((size_t)z << 16);
  } else {
    N = 1024; Kdim = 4096; Kc = 256; Wt = hf_w1; n0 = (jx - 16) << 6;
    kW0 = z * 256;
    if (kW0 >= 2048) { A = mp; S = sf2; T = tf2; kA0 = kW0 - 2048; }
    else             { A = xl; S = sf1; T = tf1; kA0 = kW0; }
    P = P_f + ((size_t)z << 17);
  }
  const int t = threadIdx.x;
  const int rowA = t >> 1, koffA = (t & 1) << 5;
  const int rowB = t >> 2, koffB = (t & 3) << 4;

  const int lane = t & 63, wav = t >> 6;
  const int r = lane & 15, kb = lane >> 4;
  int aoff[2][2], boff[2][4];
  #pragma unroll
  for (int kk = 0; kk < 2; ++kk) {
    #pragma unroll
    for (int mi = 0; mi < 2; ++mi) {
      int row = wav * 32 + mi * 16 + r;
      aoff[kk][mi] = row * 128 + ((((kk << 2) + kb) ^ (row & 7)) << 4);
    }
    #pragma unroll
    for (int ni = 0; ni < 4; ++ni) {
      int cl = ni * 16 + r;
      boff[kk][ni] = cl * 128 + ((((kk << 2) + kb) ^ (cl & 7)) << 4);
    }
  }

  f32x4 acc[2][4];
  #pragma unroll
  for (int mi = 0; mi < 2; ++mi)
    #pragma unroll
    for (int ni = 0; ni < 4; ++ni)
      acc[mi][ni] = (f32x4){0.f, 0.f, 0.f, 0.f};

  for (int kt = 0; kt < Kc; kt += 64) {
    const int ka = kA0 + kt + koffA;
    const float4* ap = (const float4*)&A[(size_t)rowA * 2048 + ka];
    const float4* sp = (const float4*)&S[ka];
    const float4* tp = (const float4*)&T[ka];
    const float4* bp = (const float4*)&Wt[(size_t)(n0 + rowB) * Kdim + kW0 + kt + koffB];  // FIX: +n0
    float4 fa[8], fb[4];
    #pragma unroll
    for (int j = 0; j < 8; ++j) fa[j] = ap[j];
    #pragma unroll
    for (int j = 0; j < 8; ++j) {
      float4 s4 = sp[j], t4 = tp[j];
      fa[j].x = fmaf(fa[j].x, s4.x, t4.x);
      fa[j].y = fmaf(fa[j].y, s4.y, t4.y);
      fa[j].z = fmaf(fa[j].z, s4.z, t4.z);
      fa[j].w = fmaf(fa[j].w, s4.w, t4.w);
    }
    #pragma unroll
    for (int j = 0; j < 4; ++j) fb[j] = bp[j];
    __syncthreads();
    #pragma unroll
    for (int j = 0; j < 4; ++j) {
      bf16x8 v;
      v[0] = (short)f2bf(fa[2*j].x);   v[1] = (short)f2bf(fa[2*j].y);
      v[2] = (short)f2bf(fa[2*j].z);   v[3] = (short)f2bf(fa[2*j].w);
      v[4] = (short)f2bf(fa[2*j+1].x); v[5] = (short)f2bf(fa[2*j+1].y);
      v[6] = (short)f2bf(fa[2*j+1].z); v[7] = (short)f2bf(fa[2*j+1].w);
      int slot = (koffA >> 3) + j;
      *(bf16x8*)((char*)As + rowA * 128 + ((slot ^ (rowA & 7)) << 4)) = v;
    }
    #pragma unroll
    for (int j = 0; j < 2; ++j) {
      bf16x8 v;
      v[0] = (short)f2bf(fb[2*j].x);   v[1] = (short)f2bf(fb[2*j].y);
      v[2] = (short)f2bf(fb[2*j].z);   v[3] = (short)f2bf(fb[2*j].w);
      v[4] = (short)f2bf(fb[2*j+1].x); v[5] = (short)f2bf(fb[2*j+1].y);
      v[6] = (short)f2bf(fb[2*j+1].z); v[7] = (short)f2bf(fb[2*j+1].w);
      int slot = (koffB >> 3) + j;
      *(bf16x8*)((char*)Bs + rowB * 128 + ((slot ^ (rowB & 7)) << 4)) = v;
    }
    __syncthreads();
    #pragma unroll
    for (int kk = 0; kk < 2; ++kk) {
      bf16x8 a0 = *(bf16x8*)((char*)As + aoff[kk][0]);
      bf16x8 a1 = *(bf16x8*)((char*)As + aoff[kk][1]);
      bf16x8 b0 = *(bf16x8*)((char*)Bs + boff[kk][0]);
      bf16x8 b1 = *(bf16x8*)((char*)Bs + boff[kk][1]);
      bf16x8 b2 = *(bf16x8*)((char*)Bs + boff[kk][2]);
      bf16x8 b3 = *(bf16x8*)((char*)Bs + boff[kk][3]);
      acc[0][0] = __builtin_amdgcn_mfma_f32_16x16x32_bf16(a0, b0, acc[0][0], 0, 0, 0);
      acc[0][1] = __builtin_amdgcn_mfma_f32_16x16x32_bf16(a0, b1, acc[0][1], 0, 0, 0);
      acc[0][2] = __builtin_amdgcn_mfma_f32_16x16x32_bf16(a0, b2, acc[0][2], 0, 0, 0);
      acc[0][3] = __builtin_amdgcn_mfma_f32_16x16x32_bf16(a0, b3, acc[0][3], 0, 0, 0);
      acc[1][0] = __builtin_amdgcn_mfma_f32_16x16x32_bf16(a1, b0, acc[1][0], 0, 0, 0);
      acc[1][1] = __builtin_amdgcn_mfma_f32_16x16x32_bf16(a1, b1, acc[1][1], 0, 0, 0);
      acc[1][2] = __builtin_amdgcn_mfma_f32_16x16x32_bf16(a1, b2, acc[1][2], 0, 0, 0);
      acc[1][3] = __builtin_amdgcn_mfma_f32_16x16x32_bf16(a1, b3, acc[1][3], 0, 0, 0);
    }
  }

  #pragma unroll
  for (int mi = 0; mi < 2; ++mi) {
    int row = wav * 32 + mi * 16 + kb * 4;
    #pragma unroll
    for (int ni = 0; ni < 4; ++ni) {
      int cl = n0 + ni * 16 + r;
      #pragma unroll
      for (int g2 = 0; g2 < 4; ++g2)
        P[(size_t)(row + g2) * N + cl] = acc[mi][ni][g2];
    }
  }
}

// ---------------------------------------------------------------------------
// K7: heads fused epilogue
// ---------------------------------------------------------------------------
__global__ __launch_bounds__(256) void heads_fused_kernel(
    const float* __restrict__ P_l, const float* __restrict__ P_h,
    const float* __restrict__ P_f,
    const float* __restrict__ bl1, const float* __restrict__ bh1,
    const float* __restrict__ bf1,
    const float* __restrict__ g2l, const float* __restrict__ b2l,
    const float* __restrict__ g2h, const float* __restrict__ b2h,
    const float* __restrict__ g2f, const float* __restrict__ b2f,
    float* __restrict__ a2_l, float* __restrict__ a2_h, float* __restrict__ a2_f) {
  const int ci = threadIdx.x & 15;
  const int g  = threadIdx.x >> 4;
  const int cj = blockIdx.x * 16 + ci;
  const float *P, *bi, *g2, *b2;
  float* out;
  int N, cc;
  if (cj < 512)       { P = P_l; bi = bl1; g2 = g2l; b2 = b2l; out = a2_l; N = 512;  cc = cj; }
  else if (cj < 1024) { P = P_h; bi = bh1; g2 = g2h; b2 = b2h; out = a2_h; N = 512;  cc = cj - 512; }
  else                { P = P_f; bi = bf1; g2 = g2f; b2 = b2f; out = a2_f; N = 1024; cc = cj - 1024; }
  const size_t sstride = (size_t)N * 128;
  float v[8];
  float s = 0.f, q = 0.f;
  const float bias = bi[cc];
  #pragma unroll
  for (int r = 0; r < 8; ++r) {
    const size_t row = g * 8 + r;
    float acc = bias;
    #pragma unroll
    for (int z = 0; z < 16; ++z)
      acc += P[(size_t)z * sstride + row * N + cc];
    v[r] = acc; s += acc; q += acc * acc;
  }
  __shared__ float ss[16][16], qq[16][16];
  __shared__ float sm[16], sr[16];
  ss[g][ci] = s; qq[g][ci] = q;
  __syncthreads();
  if (g == 0) {
    float S = 0.f, Q = 0.f;
    #pragma unroll
    for (int j = 0; j < 16; ++j) { S += ss[j][ci]; Q += qq[j][ci]; }
    float m = S * (1.f / B_DIM);
    float var = Q * (1.f / B_DIM) - m * m;
    if (var < 0.f) var = 0.f;
    sm[ci] = m; sr[ci] = rsqrtf(var + 1e-5f);
  }
  __syncthreads();
  const float m = sm[ci], rr = sr[ci];
  const float gg = g2[cc], bb = b2[cc];
  #pragma unroll
  for (int r = 0; r < 8; ++r) {
    float xn = (v[r] - m) * rr * gg + bb;
    out[(size_t)(g * 8 + r) * N + cc] = xn > 0.f ? xn : expm1f(xn);
  }
}

// ---------------------------------------------------------------------------
// K8: combined head-linear2 split-K GEMM (fp32; small). grid (12, 2, 8).
// ---------------------------------------------------------------------------
__global__ __launch_bounds__(256) void gemm_w2_kernel(
    const float* __restrict__ a2_l, const float* __restrict__ a2_h,
    const float* __restrict__ a2_f,
    const float* __restrict__ hl_w2, const float* __restrict__ hh_w2,
    const float* __restrict__ hf_w2,
    float* __restrict__ Pw) {
  const int jx = blockIdx.x;
  const int z  = blockIdx.z;
  const float *A, *Wt;
  int K, Kc, pOff, n0;
  if (jx < 4)      { A = a2_l; Wt = hl_w2; K = 512;  Kc = 64;  pOff = 0;     n0 = jx << 6; }
  else if (jx < 8) { A = a2_h; Wt = hh_w2; K = 512;  Kc = 64;  pOff = 25600; n0 = (jx - 4) << 6; }
  else             { A = a2_f; Wt = hf_w2; K = 1024; Kc = 128; pOff = 51200; n0 = (jx - 8) << 6; }
  const int kbeg = z * Kc;
  const int m0 = blockIdx.y << 6;
  __shared__ float As[32][68];
  __shared__ float Bs[32][68];
  const int t = threadIdx.x;
  const int lr = t >> 3;
  const int lk4 = (t & 7) << 2;
  const int tx = t & 15, ty = t >> 4;
  float acc[4][4] = {{0.f}};
  const float4 z4 = make_float4(0.f, 0.f, 0.f, 0.f);
  for (int k0 = kbeg; k0 < kbeg + Kc; k0 += 32) {
    float4 a0 = *(const float4*)&A[(size_t)(m0 + lr) * K + k0 + lk4];
    float4 a1 = *(const float4*)&A[(size_t)(m0 + lr + 32) * K + k0 + lk4];
    int n1 = n0 + lr, n2 = n0 + lr + 32;
    float4 b0 = (n1 < 200) ? *(const float4*)&Wt[(size_t)n1 * K + k0 + lk4] : z4;
    float4 b1 = (n2 < 200) ? *(const float4*)&Wt[(size_t)n2 * K + k0 + lk4] : z4;
    __syncthreads();
    As[lk4 + 0][lr] = a0.x; As[lk4 + 1][lr] = a0.y; As[lk4 + 2][lr] = a0.z; As[lk4 + 3][lr] = a0.w;
    As[lk4 + 0][lr + 32] = a1.x; As[lk4 + 1][lr + 32] = a1.y; As[lk4 + 2][lr + 32] = a1.z; As[lk4 + 3][lr + 32] = a1.w;
    Bs[lk4 + 0][lr] = b0.x; Bs[lk4 + 1][lr] = b0.y; Bs[lk4 + 2][lr] = b0.z; Bs[lk4 + 3][lr] = b0.w;
    Bs[lk4 + 0][lr + 32] = b1.x; Bs[lk4 + 1][lr + 32] = b1.y; Bs[lk4 + 2][lr + 32] = b1.z; Bs[lk4 + 3][lr + 32] = b1.w;
    __syncthreads();
    #pragma unroll
    for (int kk = 0; kk < 32; ++kk) {
      float4 av = *(const float4*)&As[kk][ty << 2];
      float4 bv = *(const float4*)&Bs[kk][tx << 2];
      acc[0][0] = fmaf(av.x, bv.x, acc[0][0]); acc[0][1] = fmaf(av.x, bv.y, acc[0][1]);
      acc[0][2] = fmaf(av.x, bv.z, acc[0][2]); acc[0][3] = fmaf(av.x, bv.w, acc[0][3]);
      acc[1][0] = fmaf(av.y, bv.x, acc[1][0]); acc[1][1] = fmaf(av.y, bv.y, acc[1][1]);
      acc[1][2] = fmaf(av.y, bv.z, acc[1][2]); acc[1][3] = fmaf(av.y, bv.w, acc[1][3]);
      acc[2][0] = fmaf(av.z, bv.x, acc[2][0]); acc[2][1] = fmaf(av.z, bv.y, acc[2][1]);
      acc[2][2] = fmaf(av.z, bv.z, acc[2][2]); acc[2][3] = fmaf(av.z, bv.w, acc[2][3]);
      acc[3][0] = fmaf(av.w, bv.x, acc[3][0]); acc[3][1] = fmaf(av.w, bv.y, acc[3][1]);
      acc[3][2] = fmaf(av.w, bv.z, acc[3][2]); acc[3][3] = fmaf(av.w, bv.w, acc[3][3]);
    }
  }
  float* Pz = Pw + (size_t)z * 76800 + pOff;
  #pragma unroll
  for (int i = 0; i < 4; ++i) {
    int m = m0 + (ty << 2) + i;
    #pragma unroll
    for (int j = 0; j < 4; ++j) {
      int n = n0 + (tx << 2) + j;
      if (n < 200) Pz[(size_t)m * 200 + n] = acc[i][j];
    }
  }
}

// K9: final reduce into out
__global__ void reduce_out_kernel(const float* __restrict__ P,
                                  const float* __restrict__ bl,
                                  const float* __restrict__ bh,
                                  const float* __restrict__ bf,
                                  float* __restrict__ out) {
  int i = blockIdx.x * 256 + threadIdx.x;
  if (i >= 76800) return;
  int job = i / 25600;
  int n = (i - job * 25600) % 200;
  float s = (job == 0) ? bl[n] : (job == 1) ? bh[n] : bf[n];
  for (int z = 0; z < 8; ++z) s += P[(size_t)z * 76800 + i];
  out[i] = s;
}

// ---------------------------------------------------------------------------
extern "C" void kernel_launch(void* const* d_in, const int* in_sizes, int n_in,
                              void* d_out, int out_size, void* d_ws, size_t ws_size,
                              hipStream_t stream) {
  const float* x      = (const float*)d_in[0];
  const float* g_bn_g = (const float*)d_in[1];
  const float* g_bn_b = (const float*)d_in[2];
  const float* g_w    = (const float*)d_in[3];
  const float* g_b    = (const float*)d_in[4];
  const float* e_w    = (const float*)d_in[5];
  const float* e_b    = (const float*)d_in[6];
  const float* e_g    = (const float*)d_in[7];
  const float* e_bb   = (const float*)d_in[8];
  const float* hl_g1  = (const float*)d_in[9];
  const float* hl_b1  = (const float*)d_in[10];
  const float* hl_w1  = (const float*)d_in[11];
  const float* hl_bi1 = (const float*)d_in[12];
  const float* hl_g2  = (const float*)d_in[13];
  const float* hl_b2  = (const float*)d_in[14];
  const float* hl_w2  = (const float*)d_in[15];
  const float* hl_bi2 = (const float*)d_in[16];
  const float* hh_g1  = (const float*)d_in[17];
  const float* hh_b1  = (const float*)d_in[18];
  const float* hh_w1  = (const float*)d_in[19];
  const float* hh_bi1 = (const float*)d_in[20];
  const float* hh_g2  = (const float*)d_in[21];
  const float* hh_b2  = (const float*)d_in[22];
  const float* hh_w2  = (const float*)d_in[23];
  const float* hh_bi2 = (const float*)d_in[24];
  const float* hf_g1  = (const float*)d_in[25];
  const float* hf_b1  = (const float*)d_in[26];
  const float* hf_w1  = (const float*)d_in[27];
  const float* hf_bi1 = (const float*)d_in[28];
  const float* hf_g2  = (const float*)d_in[29];
  const float* hf_b2  = (const float*)d_in[30];
  const float* hf_w2  = (const float*)d_in[31];
  const float* hf_bi2 = (const float*)d_in[32];
  float* out = (float*)d_out;

  float* W = (float*)d_ws;
  const size_t BC = (size_t)B_DIM * C_DIM;   // 262144
  float* mp   = W;
  float* ms   = mp + BC;
  float* pool = ms + BC * 4;
  float* xl   = pool + BC;
  float* a2_l = xl + BC;
  float* a2_h = a2_l + 128 * 512;
  float* a2_f = a2_h + 128 * 512;
  float* st   = a2_f + 128 * 1024;
  float* mean_mp = st;           float* rstd_mp = st + 2048;
  float* s_h  = st + 2 * 2048;   float* t_h  = st + 3 * 2048;
  float* sf2  = st + 4 * 2048;   float* tf2  = st + 5 * 2048;
  float* s_l  = st + 6 * 2048;   float* t_l  = st + 7 * 2048;
  float* sf1  = st + 8 * 2048;   float* tf1  = st + 9 * 2048;
  float* P_e  = st + 10 * 2048;                 // 8 x 262144 (reused as P_w2)
  float* P_l2 = P_e + 8 * BC;                   // 16 x 65536
  float* P_hh = P_l2 + (size_t)16 * 65536;      // 16 x 65536
  float* P_f  = P_hh + (size_t)16 * 65536;      // 16 x 131072
  float* P_w2 = P_e;

  pool_max_kernel<<<16384, 256, 0, stream>>>(x, mp, ms);

  statsmp_kernel<<<128, 256, 0, stream>>>(mp, hh_g1, hh_b1, hf_g1, hf_b1,
                                          mean_mp, rstd_mp, s_h, t_h, sf2, tf2);

  gate_select_kernel<<<128, 256, 0, stream>>>(mp, mean_mp, rstd_mp, g_bn_g, g_bn_b,
                                              g_w, g_b, ms, pool);

  gemm_e_mfma_kernel<<<dim3(32, 8), 256, 0, stream>>>(pool, e_w, P_e);

  expert_fused_kernel<<<128, 256, 0, stream>>>(P_e, e_b, e_g, e_bb,
                                               hl_g1, hl_b1, hf_g1, hf_b1,
                                               xl, s_l, t_l, sf1, tf1);

  gemm_w1_mfma_kernel<<<dim3(32, 16), 256, 0, stream>>>(
      xl, mp, s_l, t_l, s_h, t_h, sf1, tf1, sf2, tf2,
      hl_w1, hh_w1, hf_w1, P_l2, P_hh, P_f);

  heads_fused_kernel<<<128, 256, 0, stream>>>(
      P_l2, P_hh, P_f, hl_bi1, hh_bi1, hf_bi1,
      hl_g2, hl_b2, hh_g2, hh_b2, hf_g2, hf_b2,
      a2_l, a2_h, a2_f);

  gemm_w2_kernel<<<dim3(12, 2, 8), 256, 0, stream>>>(
      a2_l, a2_h, a2_f, hl_w2, hh_w2, hf_w2, P_w2);

  reduce_out_kernel<<<300, 256, 0, stream>>>(P_w2, hl_bi2, hh_bi2, hf_bi2, out);
}